// Round 2
// 439.725 us; speedup vs baseline: 1.8924x; 1.8924x over previous
//
#include <hip/hip_runtime.h>
#include <hip/hip_bf16.h>

#define Bv 1024
#define Nv 64
#define Ev 1024
#define Dv 128
#define Hv 4
#define Lv 2
#define Kv 5
#define PAD 130   // bf16 LDS row stride (unchanged: keeps CSR-gather bank behavior)

typedef __hip_bfloat16 bf16;
typedef __attribute__((ext_vector_type(8))) short bf16x8_t;  // 8 bf16 in 4 VGPRs
typedef __attribute__((ext_vector_type(4))) float f32x4_t;   // MFMA accum

__device__ __forceinline__ float b2f(bf16 v) { return __bfloat162float(v); }
__device__ __forceinline__ bf16  f2b(float v) { return __float2bfloat16(v); }

// Packed MFMA B-fragment weights (bf16 hi/lo planes) in device-global memory.
// No workspace dependence: ws_size only needs the ~4.6 KB CSR footprint.
__device__ bf16 g_pWl[(size_t)Lv * 2 * Dv * Dv];   // [L][2 planes][128*128]
__device__ bf16 g_pWr[(size_t)Lv * 2 * Dv * Dv];   // [L][2 planes][128*128]
__device__ bf16 g_pW1[(size_t)2 * 2 * Dv * Dv];    // [2 planes][256*128]

// unpack u32 = 2 packed bf16 -> 2 floats
__device__ __forceinline__ void unpack2(unsigned int u, float& lo, float& hi) {
    union { unsigned int u; float f; } a, b;
    a.u = u << 16;
    b.u = u & 0xffff0000u;
    lo = a.f; hi = b.f;
}

// load 8 consecutive bf16 (element index even) from LDS as 4 dwords -> frag
__device__ __forceinline__ bf16x8_t load_a_frag(const bf16* buf, int elem_idx) {
    const unsigned int* p = (const unsigned int*)buf;
    union { bf16x8_t v; unsigned int u[4]; } r;
    int d = elem_idx >> 1;
    r.u[0] = p[d]; r.u[1] = p[d + 1]; r.u[2] = p[d + 2]; r.u[3] = p[d + 3];
    return r.v;
}

// ---------------- CSR build: bucket edges by dst ----------------
__global__ void build_csr(const int* __restrict__ edge_index,
                          int* __restrict__ off, int* __restrict__ eid)
{
    __shared__ int cnt[Nv];
    int tid = threadIdx.x;
    if (tid < Nv) cnt[tid] = 0;
    __syncthreads();
    for (int e = tid; e < Ev; e += blockDim.x)
        atomicAdd(&cnt[edge_index[Ev + e]], 1);
    __syncthreads();
    if (tid == 0) {
        int s = 0;
        for (int t = 0; t < Nv; ++t) { int c = cnt[t]; off[t] = s; cnt[t] = s; s += c; }
        off[Nv] = s;
    }
    __syncthreads();
    for (int e = tid; e < Ev; e += blockDim.x) {
        int d = edge_index[Ev + e];
        int pos = atomicAdd(&cnt[d], 1);
        eid[pos] = e;
    }
}

// ---------------- weight packing into MFMA B-fragment order ----------------
// For a K x 128 row-major f32 matrix W[k][col], produce two bf16 planes
// (hi, lo = W - hi) in fragment order:
//   frag f = kk*8 + nt  (kk = k-step of 32, nt = 16-col tile)
//   element e = (f*64 + lane)*8 + i ;  col = nt*16 + (lane&15) ;
//   k = kk*32 + (lane>>4)*8 + i
__device__ void pack_mat(const float* __restrict__ W, bf16* __restrict__ out,
                         int K, int tid, int nth)
{
    const int total = K * 128;  // elements per plane
    for (int e = tid; e < total; e += nth) {
        int f    = e >> 9;          // 64 lanes * 8 elems
        int rem  = e & 511;
        int lane = rem >> 3;
        int i    = rem & 7;
        int kk   = f >> 3;
        int nt   = f & 7;
        int col  = nt * 16 + (lane & 15);
        int k    = kk * 32 + (lane >> 4) * 8 + i;
        float w  = W[k * 128 + col];
        bf16 hi  = f2b(w);
        out[e]         = hi;
        out[total + e] = f2b(w - b2f(hi));
    }
}

__global__ void pack_weights(const float* __restrict__ Wl, const float* __restrict__ Wr,
                             const float* __restrict__ W1)
{
    const int nth = gridDim.x * blockDim.x;
    const int tid = blockIdx.x * blockDim.x + threadIdx.x;
    for (int l = 0; l < Lv; ++l) {
        pack_mat(Wl + (size_t)l * Dv * Dv, g_pWl + (size_t)l * 2 * Dv * Dv, Dv, tid, nth);
        pack_mat(Wr + (size_t)l * Dv * Dv, g_pWr + (size_t)l * 2 * Dv * Dv, Dv, tid, nth);
    }
    pack_mat(W1, g_pW1, 2 * Dv, tid, nth);
}

// ---------------- fused per-batch-element kernel ----------------
__global__ __launch_bounds__(256)
void gat_fused(const int* __restrict__ x, const int* __restrict__ edge_index,
               const float* __restrict__ edge_attr, const float* __restrict__ attr_emb,
               const float* __restrict__ opt_emb, const float* __restrict__ prior,
               const float* __restrict__ bl, const float* __restrict__ br,
               const float* __restrict__ We, const float* __restrict__ att,
               const float* __restrict__ conv_bias, const float* __restrict__ ln_g,
               const float* __restrict__ ln_b,
               const float* __restrict__ b1, const float* __restrict__ W2,
               const float* __restrict__ b2,
               const int* __restrict__ csr_off, const int* __restrict__ csr_eid,
               float* __restrict__ out_fscale, float* __restrict__ out_rel,
               float* __restrict__ out_hatT)
{
    const int b = blockIdx.x;
    const int tid = threadIdx.x;

    __shared__ __align__(16) bf16 hs [Nv * PAD];
    __shared__ __align__(16) bf16 xls[Nv * PAD];
    __shared__ __align__(16) bf16 xrs[Nv * PAD];
    __shared__ bf16 alphas[Ev * Hv];
    __shared__ float red [Nv * Hv];
    __shared__ float red2[Nv * Hv];
    __shared__ float wecol[Dv];
    __shared__ float attv [Dv];
    __shared__ float relbuf[Nv];

    // ---- T0 -> hs ----
    for (int idx = tid; idx < Nv * Dv; idx += 256) {
        int n = idx >> 7, d = idx & 127;
        float t0 = (attr_emb[n * Dv + d] + opt_emb[(n * Kv + x[b * Nv + n]) * Dv + d])
                   * prior[n];
        hs[n * PAD + d] = f2b(t0);
    }

    for (int l = 0; l < Lv; ++l) {
        if (tid < Dv) {
            wecol[tid] = We[l * Dv + tid];
            attv[tid]  = att[l * Dv + tid];
        }
        __syncthreads();

        // ---- GEMM via MFMA: [xl | xr] = h @ [Wl | Wr] + [bl | br] ----
        // wave w (0..3): cols w*64..w*64+63 of the 256-wide concat output.
        {
            const int w = tid >> 6, lane = tid & 63;
            const int row16 = lane & 15, kg = lane >> 4;
            const bf16* pB = (w < 2) ? (g_pWl + (size_t)l * 2 * Dv * Dv)
                                     : (g_pWr + (size_t)l * 2 * Dv * Dv);
            const int wc = (w & 1) * 64;   // col offset inside the 128-wide matrix
            f32x4_t acc[4][4];
            #pragma unroll
            for (int mt = 0; mt < 4; ++mt)
                #pragma unroll
                for (int nt = 0; nt < 4; ++nt)
                    acc[mt][nt] = (f32x4_t){0.f, 0.f, 0.f, 0.f};

            #pragma unroll
            for (int kk = 0; kk < 4; ++kk) {
                const int kb = kk * 32 + kg * 8;
                bf16x8_t a[4];
                #pragma unroll
                for (int mt = 0; mt < 4; ++mt)
                    a[mt] = load_a_frag(hs, (mt * 16 + row16) * PAD + kb);
                #pragma unroll
                for (int nt = 0; nt < 4; ++nt) {
                    const int f = kk * 8 + (wc >> 4) + nt;
                    bf16x8_t bh  = *(const bf16x8_t*)&pB[(size_t)(f * 64 + lane) * 8];
                    bf16x8_t blo = *(const bf16x8_t*)&pB[Dv * Dv + (size_t)(f * 64 + lane) * 8];
                    #pragma unroll
                    for (int mt = 0; mt < 4; ++mt) {
                        acc[mt][nt] = __builtin_amdgcn_mfma_f32_16x16x32_bf16(
                                          a[mt], bh, acc[mt][nt], 0, 0, 0);
                        acc[mt][nt] = __builtin_amdgcn_mfma_f32_16x16x32_bf16(
                                          a[mt], blo, acc[mt][nt], 0, 0, 0);
                    }
                }
            }
            bf16* dst = (w < 2) ? xls : xrs;
            const float* bias = (w < 2) ? (bl + l * Dv) : (br + l * Dv);
            #pragma unroll
            for (int mt = 0; mt < 4; ++mt)
                #pragma unroll
                for (int nt = 0; nt < 4; ++nt) {
                    const int col = wc + nt * 16 + row16;
                    #pragma unroll
                    for (int r = 0; r < 4; ++r) {
                        const int row = mt * 16 + kg * 4 + r;
                        dst[row * PAD + col] = f2b(acc[mt][nt][r] + bias[col]);
                    }
                }
        }
        __syncthreads();

        // ---- per-edge per-head logits (wave-parallel) ----
        {
            const int h = tid >> 6, lane = tid & 63;
            for (int it = 0; it < Ev / 64; ++it) {
                int e = it * 64 + lane;
                int s = edge_index[e], t = edge_index[Ev + e];
                float ea = edge_attr[e];
                float acc = 0.f;
                int bs = s * PAD + h * 32, bt = t * PAD + h * 32;
                for (int c = 0; c < 32; c += 2) {
                    float xl0, xl1, xr0, xr1;
                    unpack2(*(const unsigned int*)&xls[bs + c], xl0, xl1);
                    unpack2(*(const unsigned int*)&xrs[bt + c], xr0, xr1);
                    float z0 = xl0 + xr0 + ea * wecol[h * 32 + c];
                    float z1 = xl1 + xr1 + ea * wecol[h * 32 + c + 1];
                    z0 = z0 > 0.f ? z0 : 0.2f * z0;
                    z1 = z1 > 0.f ? z1 : 0.2f * z1;
                    acc += z0 * attv[h * 32 + c] + z1 * attv[h * 32 + c + 1];
                }
                alphas[e * Hv + h] = f2b(acc);
            }
        }
        __syncthreads();

        // ---- per (dst, head) via CSR: softmax + gather + LN + ELU + residual ----
        {
            const int t = tid & 63, h = tid >> 6;
            int beg = csr_off[t], end = csr_off[t + 1];
            float mx = -3e38f;
            for (int idx = beg; idx < end; ++idx)
                mx = fmaxf(mx, b2f(alphas[csr_eid[idx] * Hv + h]));
            float den = 0.f;
            for (int idx = beg; idx < end; ++idx) {
                int e = csr_eid[idx];
                float ex = expf(b2f(alphas[e * Hv + h]) - mx);
                den += ex;
                alphas[e * Hv + h] = f2b(ex);   // edge owned by exactly one (t,h)
            }
            float acc[32];
            for (int c = 0; c < 32; ++c) acc[c] = 0.f;
            float inv_den = (end > beg) ? 1.f / den : 0.f;
            for (int idx = beg; idx < end; ++idx) {
                int e = csr_eid[idx];
                int s = edge_index[e];
                float a = b2f(alphas[e * Hv + h]) * inv_den;
                int bs = s * PAD + h * 32;
                for (int c = 0; c < 32; c += 2) {
                    float m0, m1;
                    unpack2(*(const unsigned int*)&xls[bs + c], m0, m1);
                    acc[c] += a * m0; acc[c + 1] += a * m1;
                }
            }
            float sum = 0.f, sumsq = 0.f;
            for (int c = 0; c < 32; ++c) {
                float g = acc[c] + conv_bias[l * Dv + h * 32 + c];
                acc[c] = g;
                sum += g; sumsq += g * g;
            }
            red [t * Hv + h] = sum;
            red2[t * Hv + h] = sumsq;
            __syncthreads();
            float mu = (red [t * Hv] + red [t * Hv + 1] + red [t * Hv + 2] + red [t * Hv + 3]) * (1.f / 128.f);
            float ms = (red2[t * Hv] + red2[t * Hv + 1] + red2[t * Hv + 2] + red2[t * Hv + 3]) * (1.f / 128.f);
            float rstd = rsqrtf(ms - mu * mu + 1e-5f);
            for (int c = 0; c < 32; ++c) {
                float g = (acc[c] - mu) * rstd * ln_g[l * Dv + h * 32 + c]
                          + ln_b[l * Dv + h * 32 + c];
                g = g > 0.f ? g : (expf(g) - 1.f);   // elu
                int hi = t * PAD + h * 32 + c;
                hs[hi] = f2b(b2f(hs[hi]) + g);       // residual
            }
        }
        __syncthreads();
    }

    // ---- hat_T (f32 out); T0 -> xrs; preload W2 ----
    if (tid < Dv) wecol[tid] = W2[tid];
    for (int idx = tid; idx < Nv * Dv; idx += 256) {
        int n = idx >> 7, d = idx & 127;
        float t0 = (attr_emb[n * Dv + d] + opt_emb[(n * Kv + x[b * Nv + n]) * Dv + d])
                   * prior[n];
        xrs[n * PAD + d] = f2b(t0);
        size_t rb = ((size_t)(b * Nv + n)) * (2 * Dv);
        out_hatT[rb + d]      = t0;
        out_hatT[rb + Dv + d] = b2f(hs[n * PAD + d]);
    }
    __syncthreads();

    // ---- hidden = relu([T0,h] @ W1 + b1) -> xls  (MFMA, K=256) ----
    // wave w (0..3): cols w*32..w*32+31.
    {
        const int w = tid >> 6, lane = tid & 63;
        const int row16 = lane & 15, kg = lane >> 4;
        f32x4_t acc[4][2];
        #pragma unroll
        for (int mt = 0; mt < 4; ++mt)
            #pragma unroll
            for (int nt = 0; nt < 2; ++nt)
                acc[mt][nt] = (f32x4_t){0.f, 0.f, 0.f, 0.f};

        #pragma unroll
        for (int kk = 0; kk < 8; ++kk) {
            const bf16* asrc = (kk < 4) ? xrs : hs;   // T0 then h
            const int kb = (kk & 3) * 32 + kg * 8;
            bf16x8_t a[4];
            #pragma unroll
            for (int mt = 0; mt < 4; ++mt)
                a[mt] = load_a_frag(asrc, (mt * 16 + row16) * PAD + kb);
            #pragma unroll
            for (int nt = 0; nt < 2; ++nt) {
                const int f = kk * 8 + w * 2 + nt;
                bf16x8_t bh  = *(const bf16x8_t*)&g_pW1[(size_t)(f * 64 + lane) * 8];
                bf16x8_t blo = *(const bf16x8_t*)&g_pW1[(size_t)2 * Dv * Dv + (size_t)(f * 64 + lane) * 8];
                #pragma unroll
                for (int mt = 0; mt < 4; ++mt) {
                    acc[mt][nt] = __builtin_amdgcn_mfma_f32_16x16x32_bf16(
                                      a[mt], bh, acc[mt][nt], 0, 0, 0);
                    acc[mt][nt] = __builtin_amdgcn_mfma_f32_16x16x32_bf16(
                                      a[mt], blo, acc[mt][nt], 0, 0, 0);
                }
            }
        }
        #pragma unroll
        for (int mt = 0; mt < 4; ++mt)
            #pragma unroll
            for (int nt = 0; nt < 2; ++nt) {
                const int col = w * 32 + nt * 16 + row16;
                #pragma unroll
                for (int r = 0; r < 4; ++r) {
                    const int row = mt * 16 + kg * 4 + r;
                    float v = acc[mt][nt][r] + b1[col];
                    xls[row * PAD + col] = f2b(v > 0.f ? v : 0.f);
                }
            }
    }
    __syncthreads();

    // ---- rel = sigmoid(hidden @ W2 + b2) (f32 out) ----
    {
        const int t = tid & 63, h = tid >> 6;
        float s = 0.f;
        for (int c = 0; c < 32; c += 2) {
            float h0, h1;
            unpack2(*(const unsigned int*)&xls[t * PAD + h * 32 + c], h0, h1);
            s += h0 * wecol[h * 32 + c] + h1 * wecol[h * 32 + c + 1];
        }
        red[t * Hv + h] = s;
        __syncthreads();
        if (h == 0) {
            float z = red[t * Hv] + red[t * Hv + 1] + red[t * Hv + 2] + red[t * Hv + 3]
                      + b2[0];
            float r = 1.f / (1.f + expf(-z));
            relbuf[t] = r;
            out_rel[b * Nv + t] = r;
        }
    }
    __syncthreads();

    // ---- f_scale (f32 out) ----
    if (tid < Dv) {
        float num = 0.f, den = 0.f;
        for (int n = 0; n < Nv; ++n) {
            float r = relbuf[n];
            num += b2f(hs[n * PAD + tid]) * r;
            den += r;
        }
        out_fscale[b * Dv + tid] = num / (den + 1e-8f);
    }
}

extern "C" void kernel_launch(void* const* d_in, const int* in_sizes, int n_in,
                              void* d_out, int out_size, void* d_ws, size_t ws_size,
                              hipStream_t stream)
{
    const int*   x          = (const int*)  d_in[0];
    const int*   edge_index = (const int*)  d_in[1];
    const float* edge_attr  = (const float*)d_in[2];
    const float* attr_emb   = (const float*)d_in[3];
    const float* opt_emb    = (const float*)d_in[4];
    const float* prior      = (const float*)d_in[5];
    const float* Wl         = (const float*)d_in[6];
    const float* bl         = (const float*)d_in[7];
    const float* Wr         = (const float*)d_in[8];
    const float* br         = (const float*)d_in[9];
    const float* We         = (const float*)d_in[10];
    const float* att        = (const float*)d_in[11];
    const float* conv_bias  = (const float*)d_in[12];
    const float* ln_g       = (const float*)d_in[13];
    const float* ln_b       = (const float*)d_in[14];
    const float* W1         = (const float*)d_in[15];
    const float* b1         = (const float*)d_in[16];
    const float* W2         = (const float*)d_in[17];
    const float* b2         = (const float*)d_in[18];

    int* csr_off = (int*)d_ws;          // Nv+1 ints (128 reserved)
    int* csr_eid = (int*)d_ws + 128;    // Ev ints

    float* out        = (float*)d_out;
    float* out_fscale = out;                                      // B*D
    float* out_rel    = out + (size_t)Bv * Dv;                    // B*N
    float* out_hatT   = out + (size_t)Bv * Dv + (size_t)Bv * Nv;  // B*N*2D

    build_csr<<<1, 256, 0, stream>>>(edge_index, csr_off, csr_eid);
    pack_weights<<<64, 256, 0, stream>>>(Wl, Wr, W1);
    gat_fused<<<Bv, 256, 0, stream>>>(x, edge_index, edge_attr, attr_emb, opt_emb,
                                      prior, bl, br, We, att, conv_bias,
                                      ln_g, ln_b, b1, W2, b2,
                                      csr_off, csr_eid,
                                      out_fscale, out_rel, out_hatT);
}

// Round 3
// 411.877 us; speedup vs baseline: 2.0204x; 1.0676x over previous
//
#include <hip/hip_runtime.h>
#include <hip/hip_bf16.h>

#define Bv 1024
#define Nv 64
#define Ev 1024
#define Dv 128
#define Hv 4
#define Lv 2
#define Kv 5
#define PAD 130   // bf16 LDS row stride

typedef __hip_bfloat16 bf16;
typedef __attribute__((ext_vector_type(8))) short bf16x8_t;  // 8 bf16 in 4 VGPRs
typedef __attribute__((ext_vector_type(4))) float f32x4_t;   // MFMA accum

__device__ __forceinline__ float b2f(bf16 v) { return __bfloat162float(v); }
__device__ __forceinline__ bf16  f2b(float v) { return __float2bfloat16(v); }

// Packed MFMA B-fragment weights (bf16 hi/lo planes) in device-global memory.
__device__ bf16 g_pWl[(size_t)Lv * 2 * Dv * Dv];   // [L][2 planes][128*128]
__device__ bf16 g_pWr[(size_t)Lv * 2 * Dv * Dv];   // [L][2 planes][128*128]
__device__ bf16 g_pW1[(size_t)2 * 2 * Dv * Dv];    // [2 planes][256*128]

// unpack u32 = 2 packed bf16 -> 2 floats
__device__ __forceinline__ void unpack2(unsigned int u, float& lo, float& hi) {
    union { unsigned int u; float f; } a, b;
    a.u = u << 16;
    b.u = u & 0xffff0000u;
    lo = a.f; hi = b.f;
}

// load 8 consecutive bf16 (element index even) from LDS as 4 dwords -> frag
__device__ __forceinline__ bf16x8_t load_a_frag(const bf16* buf, int elem_idx) {
    const unsigned int* p = (const unsigned int*)buf;
    union { bf16x8_t v; unsigned int u[4]; } r;
    int d = elem_idx >> 1;
    r.u[0] = p[d]; r.u[1] = p[d + 1]; r.u[2] = p[d + 2]; r.u[3] = p[d + 3];
    return r.v;
}

// ---------------- CSR build: bucket edges by dst ----------------
__global__ void build_csr(const int* __restrict__ edge_index,
                          int* __restrict__ off, int* __restrict__ eid)
{
    __shared__ int cnt[Nv];
    int tid = threadIdx.x;
    if (tid < Nv) cnt[tid] = 0;
    __syncthreads();
    for (int e = tid; e < Ev; e += blockDim.x)
        atomicAdd(&cnt[edge_index[Ev + e]], 1);
    __syncthreads();
    if (tid == 0) {
        int s = 0;
        for (int t = 0; t < Nv; ++t) { int c = cnt[t]; off[t] = s; cnt[t] = s; s += c; }
        off[Nv] = s;
    }
    __syncthreads();
    for (int e = tid; e < Ev; e += blockDim.x) {
        int d = edge_index[Ev + e];
        int pos = atomicAdd(&cnt[d], 1);
        eid[pos] = e;
    }
}

// ---------------- weight packing into MFMA B-fragment order ----------------
//   frag f = kk*8 + nt  (kk = k-step of 32, nt = 16-col tile)
//   element e = (f*64 + lane)*8 + i ;  col = nt*16 + (lane&15) ;
//   k = kk*32 + (lane>>4)*8 + i
__device__ void pack_mat(const float* __restrict__ W, bf16* __restrict__ out,
                         int K, int tid, int nth)
{
    const int total = K * 128;  // elements per plane
    for (int e = tid; e < total; e += nth) {
        int f    = e >> 9;          // 64 lanes * 8 elems
        int rem  = e & 511;
        int lane = rem >> 3;
        int i    = rem & 7;
        int kk   = f >> 3;
        int nt   = f & 7;
        int col  = nt * 16 + (lane & 15);
        int k    = kk * 32 + (lane >> 4) * 8 + i;
        float w  = W[k * 128 + col];
        bf16 hi  = f2b(w);
        out[e]         = hi;
        out[total + e] = f2b(w - b2f(hi));
    }
}

__global__ void pack_weights(const float* __restrict__ Wl, const float* __restrict__ Wr,
                             const float* __restrict__ W1)
{
    const int nth = gridDim.x * blockDim.x;
    const int tid = blockIdx.x * blockDim.x + threadIdx.x;
    for (int l = 0; l < Lv; ++l) {
        pack_mat(Wl + (size_t)l * Dv * Dv, g_pWl + (size_t)l * 2 * Dv * Dv, Dv, tid, nth);
        pack_mat(Wr + (size_t)l * Dv * Dv, g_pWr + (size_t)l * 2 * Dv * Dv, Dv, tid, nth);
    }
    pack_mat(W1, g_pW1, 2 * Dv, tid, nth);
}

// ---------------- fused per-batch-element kernel (512 thr / 8 waves) ----------------
__global__ __launch_bounds__(512, 4)
void gat_fused(const int* __restrict__ x, const int* __restrict__ edge_index,
               const float* __restrict__ edge_attr, const float* __restrict__ attr_emb,
               const float* __restrict__ opt_emb, const float* __restrict__ prior,
               const float* __restrict__ bl, const float* __restrict__ br,
               const float* __restrict__ We, const float* __restrict__ att,
               const float* __restrict__ conv_bias, const float* __restrict__ ln_g,
               const float* __restrict__ ln_b,
               const float* __restrict__ b1, const float* __restrict__ W2,
               const float* __restrict__ b2,
               const int* __restrict__ csr_off, const int* __restrict__ csr_eid,
               float* __restrict__ out_fscale, float* __restrict__ out_rel,
               float* __restrict__ out_hatT)
{
    const int b = blockIdx.x;
    const int tid = threadIdx.x;

    __shared__ __align__(16) bf16 hs [Nv * PAD];
    __shared__ __align__(16) bf16 xls[Nv * PAD];
    __shared__ __align__(16) bf16 xrs[Nv * PAD];
    __shared__ bf16 alphas[Ev * Hv];
    __shared__ float red [Nv * 8];
    __shared__ float red2[Nv * 8];
    __shared__ float wecol[Dv];
    __shared__ float attv [Dv];
    __shared__ float relbuf[Nv];

    // ---- T0 -> hs ----
    for (int idx = tid; idx < Nv * Dv; idx += 512) {
        int n = idx >> 7, d = idx & 127;
        float t0 = (attr_emb[n * Dv + d] + opt_emb[(n * Kv + x[b * Nv + n]) * Dv + d])
                   * prior[n];
        hs[n * PAD + d] = f2b(t0);
    }

    for (int l = 0; l < Lv; ++l) {
        if (tid < Dv) {
            wecol[tid] = We[l * Dv + tid];
            attv[tid]  = att[l * Dv + tid];
        }
        __syncthreads();

        // ---- GEMM via MFMA: [xl | xr] = h @ [Wl | Wr] + [bl | br] ----
        // wave w (0..7): waves 0-3 -> Wl cols (w&3)*32.. ; waves 4-7 -> Wr.
        {
            const int w = tid >> 6, lane = tid & 63;
            const int row16 = lane & 15, kg = lane >> 4;
            const bf16* pB = (w < 4) ? (g_pWl + (size_t)l * 2 * Dv * Dv)
                                     : (g_pWr + (size_t)l * 2 * Dv * Dv);
            const int wc = (w & 3) * 32;   // col offset inside the 128-wide matrix
            f32x4_t acc[4][2];
            #pragma unroll
            for (int mt = 0; mt < 4; ++mt)
                #pragma unroll
                for (int nt = 0; nt < 2; ++nt)
                    acc[mt][nt] = (f32x4_t){0.f, 0.f, 0.f, 0.f};

            #pragma unroll
            for (int kk = 0; kk < 4; ++kk) {
                const int kb = kk * 32 + kg * 8;
                bf16x8_t a[4];
                #pragma unroll
                for (int mt = 0; mt < 4; ++mt)
                    a[mt] = load_a_frag(hs, (mt * 16 + row16) * PAD + kb);
                #pragma unroll
                for (int nt = 0; nt < 2; ++nt) {
                    const int f = kk * 8 + (w & 3) * 2 + nt;
                    bf16x8_t bh  = *(const bf16x8_t*)&pB[(size_t)(f * 64 + lane) * 8];
                    bf16x8_t blo = *(const bf16x8_t*)&pB[Dv * Dv + (size_t)(f * 64 + lane) * 8];
                    #pragma unroll
                    for (int mt = 0; mt < 4; ++mt) {
                        acc[mt][nt] = __builtin_amdgcn_mfma_f32_16x16x32_bf16(
                                          a[mt], bh, acc[mt][nt], 0, 0, 0);
                        acc[mt][nt] = __builtin_amdgcn_mfma_f32_16x16x32_bf16(
                                          a[mt], blo, acc[mt][nt], 0, 0, 0);
                    }
                }
            }
            bf16* dst = (w < 4) ? xls : xrs;
            const float* bias = (w < 4) ? (bl + l * Dv) : (br + l * Dv);
            #pragma unroll
            for (int mt = 0; mt < 4; ++mt)
                #pragma unroll
                for (int nt = 0; nt < 2; ++nt) {
                    const int col = wc + nt * 16 + row16;
                    #pragma unroll
                    for (int r = 0; r < 4; ++r) {
                        const int row = mt * 16 + kg * 4 + r;
                        dst[row * PAD + col] = f2b(acc[mt][nt][r] + bias[col]);
                    }
                }
        }
        __syncthreads();

        // ---- per-edge per-head logits: 2 waves per head, 8 edge-iters each ----
        {
            const int h = (tid >> 6) & 3, half = tid >> 8, lane = tid & 63;
            for (int it = 0; it < 8; ++it) {
                int e = (half * 8 + it) * 64 + lane;
                int s = edge_index[e], t = edge_index[Ev + e];
                float ea = edge_attr[e];
                float acc = 0.f;
                int bs = s * PAD + h * 32, bt = t * PAD + h * 32;
                for (int c = 0; c < 32; c += 2) {
                    float xl0, xl1, xr0, xr1;
                    unpack2(*(const unsigned int*)&xls[bs + c], xl0, xl1);
                    unpack2(*(const unsigned int*)&xrs[bt + c], xr0, xr1);
                    float z0 = xl0 + xr0 + ea * wecol[h * 32 + c];
                    float z1 = xl1 + xr1 + ea * wecol[h * 32 + c + 1];
                    z0 = z0 > 0.f ? z0 : 0.2f * z0;
                    z1 = z1 > 0.f ? z1 : 0.2f * z1;
                    acc += z0 * attv[h * 32 + c] + z1 * attv[h * 32 + c + 1];
                }
                alphas[e * Hv + h] = f2b(acc);
            }
        }
        __syncthreads();

        // ---- per (dst, head, half): softmax-fused gather + LN + ELU + residual ----
        // Each (t,h) pair is handled by 2 threads (half 0/1), 16 channels each.
        // den is fused into the gather (scale by 1/den at the end) so alphas is
        // never mutated -> no cross-wave write/read hazard between the halves.
        {
            const int t = tid & 63, h = (tid >> 6) & 3, half = tid >> 8;
            const int ch0 = h * 32 + half * 16;
            int beg = csr_off[t], end = csr_off[t + 1];
            float mx = -3e38f;
            for (int idx = beg; idx < end; ++idx)
                mx = fmaxf(mx, b2f(alphas[csr_eid[idx] * Hv + h]));
            float acc[16];
            #pragma unroll
            for (int c = 0; c < 16; ++c) acc[c] = 0.f;
            float den = 0.f;
            for (int idx = beg; idx < end; ++idx) {
                int e = csr_eid[idx];
                int s = edge_index[e];
                float ex = expf(b2f(alphas[e * Hv + h]) - mx);
                den += ex;
                int bs = s * PAD + ch0;
                for (int c = 0; c < 16; c += 2) {
                    float m0, m1;
                    unpack2(*(const unsigned int*)&xls[bs + c], m0, m1);
                    acc[c] += ex * m0; acc[c + 1] += ex * m1;
                }
            }
            float inv_den = (end > beg) ? 1.f / den : 0.f;
            float sum = 0.f, sumsq = 0.f;
            #pragma unroll
            for (int c = 0; c < 16; ++c) {
                float g = acc[c] * inv_den + conv_bias[l * Dv + ch0 + c];
                acc[c] = g;
                sum += g; sumsq += g * g;
            }
            red [t * 8 + h * 2 + half] = sum;
            red2[t * 8 + h * 2 + half] = sumsq;
            __syncthreads();
            float mu = 0.f, ms = 0.f;
            #pragma unroll
            for (int j = 0; j < 8; ++j) { mu += red[t * 8 + j]; ms += red2[t * 8 + j]; }
            mu *= (1.f / 128.f); ms *= (1.f / 128.f);
            float rstd = rsqrtf(ms - mu * mu + 1e-5f);
            #pragma unroll
            for (int c = 0; c < 16; ++c) {
                float g = (acc[c] - mu) * rstd * ln_g[l * Dv + ch0 + c]
                          + ln_b[l * Dv + ch0 + c];
                g = g > 0.f ? g : (expf(g) - 1.f);   // elu
                int hi = t * PAD + ch0 + c;
                hs[hi] = f2b(b2f(hs[hi]) + g);       // residual
            }
        }
        __syncthreads();
    }

    // ---- hat_T (f32 out); T0 -> xrs; preload W2 ----
    if (tid < Dv) wecol[tid] = W2[tid];
    for (int idx = tid; idx < Nv * Dv; idx += 512) {
        int n = idx >> 7, d = idx & 127;
        float t0 = (attr_emb[n * Dv + d] + opt_emb[(n * Kv + x[b * Nv + n]) * Dv + d])
                   * prior[n];
        xrs[n * PAD + d] = f2b(t0);
        size_t rb = ((size_t)(b * Nv + n)) * (2 * Dv);
        out_hatT[rb + d]      = t0;
        out_hatT[rb + Dv + d] = b2f(hs[n * PAD + d]);
    }
    __syncthreads();

    // ---- hidden = relu([T0,h] @ W1 + b1) -> xls  (MFMA, K=256) ----
    // wave w (0..7): cols w*16..w*16+15.
    {
        const int w = tid >> 6, lane = tid & 63;
        const int row16 = lane & 15, kg = lane >> 4;
        f32x4_t acc[4];
        #pragma unroll
        for (int mt = 0; mt < 4; ++mt)
            acc[mt] = (f32x4_t){0.f, 0.f, 0.f, 0.f};

        #pragma unroll
        for (int kk = 0; kk < 8; ++kk) {
            const bf16* asrc = (kk < 4) ? xrs : hs;   // T0 then h
            const int kb = (kk & 3) * 32 + kg * 8;
            bf16x8_t a[4];
            #pragma unroll
            for (int mt = 0; mt < 4; ++mt)
                a[mt] = load_a_frag(asrc, (mt * 16 + row16) * PAD + kb);
            const int f = kk * 8 + w;
            bf16x8_t bh  = *(const bf16x8_t*)&g_pW1[(size_t)(f * 64 + lane) * 8];
            bf16x8_t blo = *(const bf16x8_t*)&g_pW1[(size_t)2 * Dv * Dv + (size_t)(f * 64 + lane) * 8];
            #pragma unroll
            for (int mt = 0; mt < 4; ++mt) {
                acc[mt] = __builtin_amdgcn_mfma_f32_16x16x32_bf16(a[mt], bh,  acc[mt], 0, 0, 0);
                acc[mt] = __builtin_amdgcn_mfma_f32_16x16x32_bf16(a[mt], blo, acc[mt], 0, 0, 0);
            }
        }
        #pragma unroll
        for (int mt = 0; mt < 4; ++mt) {
            const int col = w * 16 + row16;
            #pragma unroll
            for (int r = 0; r < 4; ++r) {
                const int row = mt * 16 + kg * 4 + r;
                float v = acc[mt][r] + b1[col];
                xls[row * PAD + col] = f2b(v > 0.f ? v : 0.f);
            }
        }
    }
    __syncthreads();

    // ---- rel = sigmoid(hidden @ W2 + b2) (f32 out) ----
    {
        const int t = tid & 63, h = (tid >> 6) & 3, half = tid >> 8;
        const int ch0 = h * 32 + half * 16;
        float s = 0.f;
        for (int c = 0; c < 16; c += 2) {
            float h0, h1;
            unpack2(*(const unsigned int*)&xls[t * PAD + ch0 + c], h0, h1);
            s += h0 * wecol[ch0 + c] + h1 * wecol[ch0 + c + 1];
        }
        red[t * 8 + h * 2 + half] = s;
        __syncthreads();
        if (h == 0 && half == 0) {
            float z = b2[0];
            #pragma unroll
            for (int j = 0; j < 8; ++j) z += red[t * 8 + j];
            float r = 1.f / (1.f + expf(-z));
            relbuf[t] = r;
            out_rel[b * Nv + t] = r;
        }
    }
    __syncthreads();

    // ---- f_scale (f32 out) ----
    if (tid < Dv) {
        float num = 0.f, den = 0.f;
        for (int n = 0; n < Nv; ++n) {
            float r = relbuf[n];
            num += b2f(hs[n * PAD + tid]) * r;
            den += r;
        }
        out_fscale[b * Dv + tid] = num / (den + 1e-8f);
    }
}

extern "C" void kernel_launch(void* const* d_in, const int* in_sizes, int n_in,
                              void* d_out, int out_size, void* d_ws, size_t ws_size,
                              hipStream_t stream)
{
    const int*   x          = (const int*)  d_in[0];
    const int*   edge_index = (const int*)  d_in[1];
    const float* edge_attr  = (const float*)d_in[2];
    const float* attr_emb   = (const float*)d_in[3];
    const float* opt_emb    = (const float*)d_in[4];
    const float* prior      = (const float*)d_in[5];
    const float* Wl         = (const float*)d_in[6];
    const float* bl         = (const float*)d_in[7];
    const float* Wr         = (const float*)d_in[8];
    const float* br         = (const float*)d_in[9];
    const float* We         = (const float*)d_in[10];
    const float* att        = (const float*)d_in[11];
    const float* conv_bias  = (const float*)d_in[12];
    const float* ln_g       = (const float*)d_in[13];
    const float* ln_b       = (const float*)d_in[14];
    const float* W1         = (const float*)d_in[15];
    const float* b1         = (const float*)d_in[16];
    const float* W2         = (const float*)d_in[17];
    const float* b2         = (const float*)d_in[18];

    int* csr_off = (int*)d_ws;          // Nv+1 ints (128 reserved)
    int* csr_eid = (int*)d_ws + 128;    // Ev ints

    float* out        = (float*)d_out;
    float* out_fscale = out;                                      // B*D
    float* out_rel    = out + (size_t)Bv * Dv;                    // B*N
    float* out_hatT   = out + (size_t)Bv * Dv + (size_t)Bv * Nv;  // B*N*2D

    build_csr<<<1, 256, 0, stream>>>(edge_index, csr_off, csr_eid);
    pack_weights<<<64, 256, 0, stream>>>(Wl, Wr, W1);
    gat_fused<<<Bv, 512, 0, stream>>>(x, edge_index, edge_attr, attr_emb, opt_emb,
                                      prior, bl, br, We, att, conv_bias,
                                      ln_g, ln_b, b1, W2, b2,
                                      csr_off, csr_eid,
                                      out_fscale, out_rel, out_hatT);
}

// Round 4
// 309.573 us; speedup vs baseline: 2.6880x; 1.3305x over previous
//
#include <hip/hip_runtime.h>
#include <hip/hip_bf16.h>

#define Bv 1024
#define Nv 64
#define Ev 1024
#define Dv 128
#define Hv 4
#define Lv 2
#define Kv 5
#define PAD 130   // bf16 LDS row stride

typedef __hip_bfloat16 bf16;
typedef __attribute__((ext_vector_type(8))) short bf16x8_t;  // 8 bf16 in 4 VGPRs
typedef __attribute__((ext_vector_type(4))) float f32x4_t;   // MFMA accum

__device__ __forceinline__ float b2f(bf16 v) { return __bfloat162float(v); }
__device__ __forceinline__ bf16  f2b(float v) { return __float2bfloat16(v); }

// Packed MFMA B-fragment weights (bf16 hi/lo planes) in device-global memory.
__device__ bf16 g_pWl[(size_t)Lv * 2 * Dv * Dv];   // [L][2 planes][128*128]
__device__ bf16 g_pWr[(size_t)Lv * 2 * Dv * Dv];   // [L][2 planes][128*128]
__device__ bf16 g_pW1[(size_t)2 * 2 * Dv * Dv];    // [2 planes][256*128]

// unpack u32 = 2 packed bf16 -> 2 floats
__device__ __forceinline__ void unpack2(unsigned int u, float& lo, float& hi) {
    union { unsigned int u; float f; } a, b;
    a.u = u << 16;
    b.u = u & 0xffff0000u;
    lo = a.f; hi = b.f;
}

// load 8 consecutive bf16 (element index even) from LDS as 4 dwords -> frag
__device__ __forceinline__ bf16x8_t load_a_frag(const bf16* buf, int elem_idx) {
    const unsigned int* p = (const unsigned int*)buf;
    union { bf16x8_t v; unsigned int u[4]; } r;
    int d = elem_idx >> 1;
    r.u[0] = p[d]; r.u[1] = p[d + 1]; r.u[2] = p[d + 2]; r.u[3] = p[d + 3];
    return r.v;
}

// ---------------- CSR build: bucket edges by dst ----------------
__global__ void build_csr(const int* __restrict__ edge_index,
                          int* __restrict__ off, int* __restrict__ eid)
{
    __shared__ int cnt[Nv];
    int tid = threadIdx.x;
    if (tid < Nv) cnt[tid] = 0;
    __syncthreads();
    for (int e = tid; e < Ev; e += blockDim.x)
        atomicAdd(&cnt[edge_index[Ev + e]], 1);
    __syncthreads();
    if (tid == 0) {
        int s = 0;
        for (int t = 0; t < Nv; ++t) { int c = cnt[t]; off[t] = s; cnt[t] = s; s += c; }
        off[Nv] = s;
    }
    __syncthreads();
    for (int e = tid; e < Ev; e += blockDim.x) {
        int d = edge_index[Ev + e];
        int pos = atomicAdd(&cnt[d], 1);
        eid[pos] = e;
    }
}

// ---------------- weight packing into MFMA B-fragment order ----------------
//   frag f = kk*8 + nt  (kk = k-step of 32, nt = 16-col tile)
//   element e = (f*64 + lane)*8 + i ;  col = nt*16 + (lane&15) ;
//   k = kk*32 + (lane>>4)*8 + i
__device__ void pack_mat(const float* __restrict__ W, bf16* __restrict__ out,
                         int K, int tid, int nth)
{
    const int total = K * 128;  // elements per plane
    for (int e = tid; e < total; e += nth) {
        int f    = e >> 9;          // 64 lanes * 8 elems
        int rem  = e & 511;
        int lane = rem >> 3;
        int i    = rem & 7;
        int kk   = f >> 3;
        int nt   = f & 7;
        int col  = nt * 16 + (lane & 15);
        int k    = kk * 32 + (lane >> 4) * 8 + i;
        float w  = W[k * 128 + col];
        bf16 hi  = f2b(w);
        out[e]         = hi;
        out[total + e] = f2b(w - b2f(hi));
    }
}

__global__ void pack_weights(const float* __restrict__ Wl, const float* __restrict__ Wr,
                             const float* __restrict__ W1)
{
    const int nth = gridDim.x * blockDim.x;
    const int tid = blockIdx.x * blockDim.x + threadIdx.x;
    for (int l = 0; l < Lv; ++l) {
        pack_mat(Wl + (size_t)l * Dv * Dv, g_pWl + (size_t)l * 2 * Dv * Dv, Dv, tid, nth);
        pack_mat(Wr + (size_t)l * Dv * Dv, g_pWr + (size_t)l * 2 * Dv * Dv, Dv, tid, nth);
    }
    pack_mat(W1, g_pW1, 2 * Dv, tid, nth);
}

// ---------------- fused per-batch-element kernel (512 thr / 8 waves) ----------------
// launch_bounds (512, 2): VGPR budget 256. (512,4) forced 64 VGPRs -> ~776 MB/dispatch
// of scratch spill traffic (FETCH 325 MB, WRITE 523 MB) -> HBM-bound. Do not tighten.
__global__ __launch_bounds__(512, 2)
void gat_fused(const int* __restrict__ x, const int* __restrict__ edge_index,
               const float* __restrict__ edge_attr, const float* __restrict__ attr_emb,
               const float* __restrict__ opt_emb, const float* __restrict__ prior,
               const float* __restrict__ bl, const float* __restrict__ br,
               const float* __restrict__ We, const float* __restrict__ att,
               const float* __restrict__ conv_bias, const float* __restrict__ ln_g,
               const float* __restrict__ ln_b,
               const float* __restrict__ b1, const float* __restrict__ W2,
               const float* __restrict__ b2,
               const int* __restrict__ csr_off, const int* __restrict__ csr_eid,
               float* __restrict__ out_fscale, float* __restrict__ out_rel,
               float* __restrict__ out_hatT)
{
    const int b = blockIdx.x;
    const int tid = threadIdx.x;

    __shared__ __align__(16) bf16 hs [Nv * PAD];
    __shared__ __align__(16) bf16 xls[Nv * PAD];
    __shared__ __align__(16) bf16 xrs[Nv * PAD];
    __shared__ bf16 alphas[Ev * Hv];
    __shared__ float red [Nv * 8];
    __shared__ float red2[Nv * 8];
    __shared__ float wecol[Dv];
    __shared__ float attv [Dv];
    __shared__ float relbuf[Nv];

    // ---- T0 -> hs ----
    for (int idx = tid; idx < Nv * Dv; idx += 512) {
        int n = idx >> 7, d = idx & 127;
        float t0 = (attr_emb[n * Dv + d] + opt_emb[(n * Kv + x[b * Nv + n]) * Dv + d])
                   * prior[n];
        hs[n * PAD + d] = f2b(t0);
    }

    for (int l = 0; l < Lv; ++l) {
        if (tid < Dv) {
            wecol[tid] = We[l * Dv + tid];
            attv[tid]  = att[l * Dv + tid];
        }
        __syncthreads();

        // ---- GEMM via MFMA: [xl | xr] = h @ [Wl | Wr] + [bl | br] ----
        // wave w (0..7): waves 0-3 -> Wl cols (w&3)*32.. ; waves 4-7 -> Wr.
        {
            const int w = tid >> 6, lane = tid & 63;
            const int row16 = lane & 15, kg = lane >> 4;
            const bf16* pB = (w < 4) ? (g_pWl + (size_t)l * 2 * Dv * Dv)
                                     : (g_pWr + (size_t)l * 2 * Dv * Dv);
            const int wc = (w & 3) * 32;   // col offset inside the 128-wide matrix
            f32x4_t acc[4][2];
            #pragma unroll
            for (int mt = 0; mt < 4; ++mt)
                #pragma unroll
                for (int nt = 0; nt < 2; ++nt)
                    acc[mt][nt] = (f32x4_t){0.f, 0.f, 0.f, 0.f};

            #pragma unroll
            for (int kk = 0; kk < 4; ++kk) {
                const int kb = kk * 32 + kg * 8;
                bf16x8_t a[4];
                #pragma unroll
                for (int mt = 0; mt < 4; ++mt)
                    a[mt] = load_a_frag(hs, (mt * 16 + row16) * PAD + kb);
                #pragma unroll
                for (int nt = 0; nt < 2; ++nt) {
                    const int f = kk * 8 + (w & 3) * 2 + nt;
                    bf16x8_t bh  = *(const bf16x8_t*)&pB[(size_t)(f * 64 + lane) * 8];
                    bf16x8_t blo = *(const bf16x8_t*)&pB[Dv * Dv + (size_t)(f * 64 + lane) * 8];
                    #pragma unroll
                    for (int mt = 0; mt < 4; ++mt) {
                        acc[mt][nt] = __builtin_amdgcn_mfma_f32_16x16x32_bf16(
                                          a[mt], bh, acc[mt][nt], 0, 0, 0);
                        acc[mt][nt] = __builtin_amdgcn_mfma_f32_16x16x32_bf16(
                                          a[mt], blo, acc[mt][nt], 0, 0, 0);
                    }
                }
            }
            bf16* dst = (w < 4) ? xls : xrs;
            const float* bias = (w < 4) ? (bl + l * Dv) : (br + l * Dv);
            #pragma unroll
            for (int mt = 0; mt < 4; ++mt)
                #pragma unroll
                for (int nt = 0; nt < 2; ++nt) {
                    const int col = wc + nt * 16 + row16;
                    #pragma unroll
                    for (int r = 0; r < 4; ++r) {
                        const int row = mt * 16 + kg * 4 + r;
                        dst[row * PAD + col] = f2b(acc[mt][nt][r] + bias[col]);
                    }
                }
        }
        __syncthreads();

        // ---- per-edge per-head logits: 2 waves per head, 8 edge-iters each ----
        {
            const int h = (tid >> 6) & 3, half = tid >> 8, lane = tid & 63;
            for (int it = 0; it < 8; ++it) {
                int e = (half * 8 + it) * 64 + lane;
                int s = edge_index[e], t = edge_index[Ev + e];
                float ea = edge_attr[e];
                float acc = 0.f;
                int bs = s * PAD + h * 32, bt = t * PAD + h * 32;
                #pragma unroll
                for (int c = 0; c < 32; c += 2) {
                    float xl0, xl1, xr0, xr1;
                    unpack2(*(const unsigned int*)&xls[bs + c], xl0, xl1);
                    unpack2(*(const unsigned int*)&xrs[bt + c], xr0, xr1);
                    float z0 = xl0 + xr0 + ea * wecol[h * 32 + c];
                    float z1 = xl1 + xr1 + ea * wecol[h * 32 + c + 1];
                    z0 = z0 > 0.f ? z0 : 0.2f * z0;
                    z1 = z1 > 0.f ? z1 : 0.2f * z1;
                    acc += z0 * attv[h * 32 + c] + z1 * attv[h * 32 + c + 1];
                }
                alphas[e * Hv + h] = f2b(acc);
            }
        }
        __syncthreads();

        // ---- per (dst, head, half): softmax-fused gather + LN + ELU + residual ----
        // Each (t,h) pair is handled by 2 threads (half 0/1), 16 channels each.
        // den is fused into the gather (scale by 1/den at the end) so alphas is
        // never mutated -> no cross-wave write/read hazard between the halves.
        {
            const int t = tid & 63, h = (tid >> 6) & 3, half = tid >> 8;
            const int ch0 = h * 32 + half * 16;
            int beg = csr_off[t], end = csr_off[t + 1];
            float mx = -3e38f;
            for (int idx = beg; idx < end; ++idx)
                mx = fmaxf(mx, b2f(alphas[csr_eid[idx] * Hv + h]));
            float acc[16];
            #pragma unroll
            for (int c = 0; c < 16; ++c) acc[c] = 0.f;
            float den = 0.f;
            for (int idx = beg; idx < end; ++idx) {
                int e = csr_eid[idx];
                int s = edge_index[e];
                float ex = expf(b2f(alphas[e * Hv + h]) - mx);
                den += ex;
                int bs = s * PAD + ch0;
                #pragma unroll
                for (int c = 0; c < 16; c += 2) {
                    float m0, m1;
                    unpack2(*(const unsigned int*)&xls[bs + c], m0, m1);
                    acc[c] += ex * m0; acc[c + 1] += ex * m1;
                }
            }
            float inv_den = (end > beg) ? 1.f / den : 0.f;
            float sum = 0.f, sumsq = 0.f;
            #pragma unroll
            for (int c = 0; c < 16; ++c) {
                float g = acc[c] * inv_den + conv_bias[l * Dv + ch0 + c];
                acc[c] = g;
                sum += g; sumsq += g * g;
            }
            red [t * 8 + h * 2 + half] = sum;
            red2[t * 8 + h * 2 + half] = sumsq;
            __syncthreads();
            float mu = 0.f, ms = 0.f;
            #pragma unroll
            for (int j = 0; j < 8; ++j) { mu += red[t * 8 + j]; ms += red2[t * 8 + j]; }
            mu *= (1.f / 128.f); ms *= (1.f / 128.f);
            float rstd = rsqrtf(ms - mu * mu + 1e-5f);
            #pragma unroll
            for (int c = 0; c < 16; ++c) {
                float g = (acc[c] - mu) * rstd * ln_g[l * Dv + ch0 + c]
                          + ln_b[l * Dv + ch0 + c];
                g = g > 0.f ? g : (expf(g) - 1.f);   // elu
                int hi = t * PAD + ch0 + c;
                hs[hi] = f2b(b2f(hs[hi]) + g);       // residual
            }
        }
        __syncthreads();
    }

    // ---- hat_T (f32 out); T0 -> xrs; preload W2 ----
    if (tid < Dv) wecol[tid] = W2[tid];
    for (int idx = tid; idx < Nv * Dv; idx += 512) {
        int n = idx >> 7, d = idx & 127;
        float t0 = (attr_emb[n * Dv + d] + opt_emb[(n * Kv + x[b * Nv + n]) * Dv + d])
                   * prior[n];
        xrs[n * PAD + d] = f2b(t0);
        size_t rb = ((size_t)(b * Nv + n)) * (2 * Dv);
        out_hatT[rb + d]      = t0;
        out_hatT[rb + Dv + d] = b2f(hs[n * PAD + d]);
    }
    __syncthreads();

    // ---- hidden = relu([T0,h] @ W1 + b1) -> xls  (MFMA, K=256) ----
    // wave w (0..7): cols w*16..w*16+15.
    {
        const int w = tid >> 6, lane = tid & 63;
        const int row16 = lane & 15, kg = lane >> 4;
        f32x4_t acc[4];
        #pragma unroll
        for (int mt = 0; mt < 4; ++mt)
            acc[mt] = (f32x4_t){0.f, 0.f, 0.f, 0.f};

        #pragma unroll
        for (int kk = 0; kk < 8; ++kk) {
            const bf16* asrc = (kk < 4) ? xrs : hs;   // T0 then h
            const int kb = (kk & 3) * 32 + kg * 8;
            bf16x8_t a[4];
            #pragma unroll
            for (int mt = 0; mt < 4; ++mt)
                a[mt] = load_a_frag(asrc, (mt * 16 + row16) * PAD + kb);
            const int f = kk * 8 + w;
            bf16x8_t bh  = *(const bf16x8_t*)&g_pW1[(size_t)(f * 64 + lane) * 8];
            bf16x8_t blo = *(const bf16x8_t*)&g_pW1[(size_t)2 * Dv * Dv + (size_t)(f * 64 + lane) * 8];
            #pragma unroll
            for (int mt = 0; mt < 4; ++mt) {
                acc[mt] = __builtin_amdgcn_mfma_f32_16x16x32_bf16(a[mt], bh,  acc[mt], 0, 0, 0);
                acc[mt] = __builtin_amdgcn_mfma_f32_16x16x32_bf16(a[mt], blo, acc[mt], 0, 0, 0);
            }
        }
        #pragma unroll
        for (int mt = 0; mt < 4; ++mt) {
            const int col = w * 16 + row16;
            #pragma unroll
            for (int r = 0; r < 4; ++r) {
                const int row = mt * 16 + kg * 4 + r;
                float v = acc[mt][r] + b1[col];
                xls[row * PAD + col] = f2b(v > 0.f ? v : 0.f);
            }
        }
    }
    __syncthreads();

    // ---- rel = sigmoid(hidden @ W2 + b2) (f32 out) ----
    {
        const int t = tid & 63, h = (tid >> 6) & 3, half = tid >> 8;
        const int ch0 = h * 32 + half * 16;
        float s = 0.f;
        #pragma unroll
        for (int c = 0; c < 16; c += 2) {
            float h0, h1;
            unpack2(*(const unsigned int*)&xls[t * PAD + ch0 + c], h0, h1);
            s += h0 * wecol[ch0 + c] + h1 * wecol[ch0 + c + 1];
        }
        red[t * 8 + h * 2 + half] = s;
        __syncthreads();
        if (h == 0 && half == 0) {
            float z = b2[0];
            #pragma unroll
            for (int j = 0; j < 8; ++j) z += red[t * 8 + j];
            float r = 1.f / (1.f + expf(-z));
            relbuf[t] = r;
            out_rel[b * Nv + t] = r;
        }
    }
    __syncthreads();

    // ---- f_scale (f32 out) ----
    if (tid < Dv) {
        float num = 0.f, den = 0.f;
        for (int n = 0; n < Nv; ++n) {
            float r = relbuf[n];
            num += b2f(hs[n * PAD + tid]) * r;
            den += r;
        }
        out_fscale[b * Dv + tid] = num / (den + 1e-8f);
    }
}

extern "C" void kernel_launch(void* const* d_in, const int* in_sizes, int n_in,
                              void* d_out, int out_size, void* d_ws, size_t ws_size,
                              hipStream_t stream)
{
    const int*   x          = (const int*)  d_in[0];
    const int*   edge_index = (const int*)  d_in[1];
    const float* edge_attr  = (const float*)d_in[2];
    const float* attr_emb   = (const float*)d_in[3];
    const float* opt_emb    = (const float*)d_in[4];
    const float* prior      = (const float*)d_in[5];
    const float* Wl         = (const float*)d_in[6];
    const float* bl         = (const float*)d_in[7];
    const float* Wr         = (const float*)d_in[8];
    const float* br         = (const float*)d_in[9];
    const float* We         = (const float*)d_in[10];
    const float* att        = (const float*)d_in[11];
    const float* conv_bias  = (const float*)d_in[12];
    const float* ln_g       = (const float*)d_in[13];
    const float* ln_b       = (const float*)d_in[14];
    const float* W1         = (const float*)d_in[15];
    const float* b1         = (const float*)d_in[16];
    const float* W2         = (const float*)d_in[17];
    const float* b2         = (const float*)d_in[18];

    int* csr_off = (int*)d_ws;          // Nv+1 ints (128 reserved)
    int* csr_eid = (int*)d_ws + 128;    // Ev ints

    float* out        = (float*)d_out;
    float* out_fscale = out;                                      // B*D
    float* out_rel    = out + (size_t)Bv * Dv;                    // B*N
    float* out_hatT   = out + (size_t)Bv * Dv + (size_t)Bv * Nv;  // B*N*2D

    build_csr<<<1, 256, 0, stream>>>(edge_index, csr_off, csr_eid);
    pack_weights<<<64, 256, 0, stream>>>(Wl, Wr, W1);
    gat_fused<<<Bv, 512, 0, stream>>>(x, edge_index, edge_attr, attr_emb, opt_emb,
                                      prior, bl, br, We, att, conv_bias,
                                      ln_g, ln_b, b1, W2, b2,
                                      csr_off, csr_eid,
                                      out_fscale, out_rel, out_hatT);
}

// Round 5
// 302.733 us; speedup vs baseline: 2.7488x; 1.0226x over previous
//
#include <hip/hip_runtime.h>
#include <hip/hip_bf16.h>

#define Bv 1024
#define Nv 64
#define Ev 1024
#define Dv 128
#define Hv 4
#define Lv 2
#define Kv 5
#define PAD 130   // bf16 LDS row stride

typedef __hip_bfloat16 bf16;
typedef __attribute__((ext_vector_type(8))) short bf16x8_t;  // 8 bf16 in 4 VGPRs
typedef __attribute__((ext_vector_type(4))) float f32x4_t;   // MFMA accum
typedef __attribute__((ext_vector_type(2))) float f32x2_t;   // packed dual-f32 (v_pk_*)

__device__ __forceinline__ float b2f(bf16 v) { return __bfloat162float(v); }
__device__ __forceinline__ bf16  f2b(float v) { return __float2bfloat16(v); }

// Packed MFMA B-fragment weights (bf16 hi/lo planes) in device-global memory.
__device__ bf16 g_pWl[(size_t)Lv * 2 * Dv * Dv];   // [L][2 planes][128*128]
__device__ bf16 g_pWr[(size_t)Lv * 2 * Dv * Dv];   // [L][2 planes][128*128]
__device__ bf16 g_pW1[(size_t)2 * 2 * Dv * Dv];    // [2 planes][256*128]
__device__ float g_K[Lv * Hv];                     // 0.2 * sum_c att[l,h,c]*We[l,h,c]

// unpack u32 = 2 packed bf16 -> 2 floats
__device__ __forceinline__ void unpack2(unsigned int u, float& lo, float& hi) {
    union { unsigned int u; float f; } a, b;
    a.u = u << 16;
    b.u = u & 0xffff0000u;
    lo = a.f; hi = b.f;
}

__device__ __forceinline__ f32x2_t unpack2v(unsigned int u) {
    union { unsigned int u; float f; } a, b;
    a.u = u << 16;
    b.u = u & 0xffff0000u;
    return (f32x2_t){a.f, b.f};
}

// pack 2 floats -> u32 of 2 bf16 (lo = elem0, hi = elem1)
__device__ __forceinline__ unsigned int pack2v(f32x2_t v) {
    union { bf16 b; unsigned short u; } lo, hi;
    lo.b = f2b(v.x); hi.b = f2b(v.y);
    return (unsigned int)lo.u | ((unsigned int)hi.u << 16);
}

// load 8 consecutive bf16 (element index even) from LDS as 4 dwords -> frag
__device__ __forceinline__ bf16x8_t load_a_frag(const bf16* buf, int elem_idx) {
    const unsigned int* p = (const unsigned int*)buf;
    union { bf16x8_t v; unsigned int u[4]; } r;
    int d = elem_idx >> 1;
    r.u[0] = p[d]; r.u[1] = p[d + 1]; r.u[2] = p[d + 2]; r.u[3] = p[d + 3];
    return r.v;
}

// ---------------- weight packing into MFMA B-fragment order ----------------
//   frag f = kk*8 + nt  (kk = k-step of 32, nt = 16-col tile)
//   element e = (f*64 + lane)*8 + i ;  col = nt*16 + (lane&15) ;
//   k = kk*32 + (lane>>4)*8 + i
__device__ void pack_mat(const float* __restrict__ W, bf16* __restrict__ out,
                         int K, int tid, int nth)
{
    const int total = K * 128;  // elements per plane
    for (int e = tid; e < total; e += nth) {
        int f    = e >> 9;          // 64 lanes * 8 elems
        int rem  = e & 511;
        int lane = rem >> 3;
        int i    = rem & 7;
        int kk   = f >> 3;
        int nt   = f & 7;
        int col  = nt * 16 + (lane & 15);
        int k    = kk * 32 + (lane >> 4) * 8 + i;
        float w  = W[k * 128 + col];
        bf16 hi  = f2b(w);
        out[e]         = hi;
        out[total + e] = f2b(w - b2f(hi));
    }
}

// ---------------- prep: block 0 = CSR build; blocks 1..64 = weight packing ----------------
__global__ void prep(const int* __restrict__ edge_index,
                     int* __restrict__ off, int* __restrict__ eid,
                     const float* __restrict__ Wl, const float* __restrict__ Wr,
                     const float* __restrict__ W1, const float* __restrict__ We,
                     const float* __restrict__ att)
{
    const int bid = blockIdx.x;
    if (bid == 0) {
        __shared__ int cnt[Nv];
        int tid = threadIdx.x;
        if (tid < Nv) cnt[tid] = 0;
        __syncthreads();
        for (int e = tid; e < Ev; e += blockDim.x)
            atomicAdd(&cnt[edge_index[Ev + e]], 1);
        __syncthreads();
        if (tid == 0) {
            int s = 0;
            for (int t = 0; t < Nv; ++t) { int c = cnt[t]; off[t] = s; cnt[t] = s; s += c; }
            off[Nv] = s;
        }
        __syncthreads();
        for (int e = tid; e < Ev; e += blockDim.x) {
            int d = edge_index[Ev + e];
            int pos = atomicAdd(&cnt[d], 1);
            eid[pos] = e;
        }
        return;
    }
    const int nth = 64 * 256;
    const int tid = (bid - 1) * 256 + threadIdx.x;
    for (int l = 0; l < Lv; ++l) {
        pack_mat(Wl + (size_t)l * Dv * Dv, g_pWl + (size_t)l * 2 * Dv * Dv, Dv, tid, nth);
        pack_mat(Wr + (size_t)l * Dv * Dv, g_pWr + (size_t)l * 2 * Dv * Dv, Dv, tid, nth);
    }
    pack_mat(W1, g_pW1, 2 * Dv, tid, nth);
    if (bid == 1 && threadIdx.x < Lv * Hv) {
        int l = threadIdx.x / Hv, h = threadIdx.x % Hv;
        float k = 0.f;
        for (int c = 0; c < 32; ++c)
            k += att[l * Dv + h * 32 + c] * We[l * Dv + h * 32 + c];
        g_K[threadIdx.x] = 0.2f * k;
    }
}

// ---------------- fused per-batch-element kernel (512 thr / 8 waves) ----------------
// launch_bounds (512, 2): VGPR budget 256. (512,4) forced 64 VGPRs -> ~776 MB/dispatch
// of scratch spill traffic -> HBM-bound. Do not tighten.
__global__ __launch_bounds__(512, 2)
void gat_fused(const int* __restrict__ x, const int* __restrict__ edge_index,
               const float* __restrict__ edge_attr, const float* __restrict__ attr_emb,
               const float* __restrict__ opt_emb, const float* __restrict__ prior,
               const float* __restrict__ bl, const float* __restrict__ br,
               const float* __restrict__ conv_bias, const float* __restrict__ ln_g,
               const float* __restrict__ ln_b,
               const float* __restrict__ b1, const float* __restrict__ W2,
               const float* __restrict__ b2,
               const float* __restrict__ We, const float* __restrict__ att,
               const int* __restrict__ csr_off, const int* __restrict__ csr_eid,
               float* __restrict__ out_fscale, float* __restrict__ out_rel,
               float* __restrict__ out_hatT)
{
    const int b = blockIdx.x;
    const int tid = threadIdx.x;

    __shared__ __align__(16) bf16 hs [Nv * PAD];
    __shared__ __align__(16) bf16 xls[Nv * PAD];
    __shared__ __align__(16) bf16 xrs[Nv * PAD];
    __shared__ bf16 alphas[Ev * Hv];
    __shared__ __align__(16) float red [Nv * 8];   // also: dotL during logits
    __shared__ __align__(16) float red2[Nv * 8];   // also: dotR during logits
    __shared__ __align__(16) float wecol[Dv];
    __shared__ __align__(16) float attv [Dv];
    __shared__ float relbuf[Nv];

    // ---- T0 -> hs ----
    for (int idx = tid; idx < Nv * Dv; idx += 512) {
        int n = idx >> 7, d = idx & 127;
        float t0 = (attr_emb[n * Dv + d] + opt_emb[(n * Kv + x[b * Nv + n]) * Dv + d])
                   * prior[n];
        hs[n * PAD + d] = f2b(t0);
    }

    for (int l = 0; l < Lv; ++l) {
        if (tid < Dv) {
            wecol[tid] = We[l * Dv + tid];
            attv[tid]  = att[l * Dv + tid];
        }
        __syncthreads();

        // ---- GEMM via MFMA: [xl | xr] = h @ [Wl | Wr] + [bl | br] ----
        // wave w (0..7): waves 0-3 -> Wl cols (w&3)*32.. ; waves 4-7 -> Wr.
        {
            const int w = tid >> 6, lane = tid & 63;
            const int row16 = lane & 15, kg = lane >> 4;
            const bf16* pB = (w < 4) ? (g_pWl + (size_t)l * 2 * Dv * Dv)
                                     : (g_pWr + (size_t)l * 2 * Dv * Dv);
            const int wc = (w & 3) * 32;
            f32x4_t acc[4][2];
            #pragma unroll
            for (int mt = 0; mt < 4; ++mt)
                #pragma unroll
                for (int nt = 0; nt < 2; ++nt)
                    acc[mt][nt] = (f32x4_t){0.f, 0.f, 0.f, 0.f};

            #pragma unroll
            for (int kk = 0; kk < 4; ++kk) {
                const int kb = kk * 32 + kg * 8;
                bf16x8_t a[4];
                #pragma unroll
                for (int mt = 0; mt < 4; ++mt)
                    a[mt] = load_a_frag(hs, (mt * 16 + row16) * PAD + kb);
                #pragma unroll
                for (int nt = 0; nt < 2; ++nt) {
                    const int f = kk * 8 + (w & 3) * 2 + nt;
                    bf16x8_t bh  = *(const bf16x8_t*)&pB[(size_t)(f * 64 + lane) * 8];
                    bf16x8_t blo = *(const bf16x8_t*)&pB[Dv * Dv + (size_t)(f * 64 + lane) * 8];
                    #pragma unroll
                    for (int mt = 0; mt < 4; ++mt) {
                        acc[mt][nt] = __builtin_amdgcn_mfma_f32_16x16x32_bf16(
                                          a[mt], bh, acc[mt][nt], 0, 0, 0);
                        acc[mt][nt] = __builtin_amdgcn_mfma_f32_16x16x32_bf16(
                                          a[mt], blo, acc[mt][nt], 0, 0, 0);
                    }
                }
            }
            bf16* dst = (w < 4) ? xls : xrs;
            const float* bias = (w < 4) ? (bl + l * Dv) : (br + l * Dv);
            #pragma unroll
            for (int mt = 0; mt < 4; ++mt)
                #pragma unroll
                for (int nt = 0; nt < 2; ++nt) {
                    const int col = wc + nt * 16 + row16;
                    #pragma unroll
                    for (int r = 0; r < 4; ++r) {
                        const int row = mt * 16 + kg * 4 + r;
                        dst[row * PAD + col] = f2b(acc[mt][nt][r] + bias[col]);
                    }
                }
        }
        __syncthreads();

        // ---- per (n,h,half): linear att-dots (factored leaky-relu) -> red/red2 ----
        {
            const int t = tid & 63, h = (tid >> 6) & 3, half = tid >> 8;
            const int ch0 = h * 32 + half * 16;
            f32x2_t dl2 = {0.f, 0.f}, dr2 = {0.f, 0.f};
            #pragma unroll
            for (int c = 0; c < 16; c += 2) {
                f32x2_t a2 = *(const f32x2_t*)&attv[ch0 + c];
                dl2 += a2 * unpack2v(*(const unsigned int*)&xls[t * PAD + ch0 + c]);
                dr2 += a2 * unpack2v(*(const unsigned int*)&xrs[t * PAD + ch0 + c]);
            }
            red [t * 8 + h * 2 + half] = dl2.x + dl2.y;
            red2[t * 8 + h * 2 + half] = dr2.x + dr2.y;
        }
        __syncthreads();

        // ---- per-edge per-head logits (packed f32, factored leaky) ----
        // alpha = 0.2*(dotL[s]+dotR[t]+ea*K) + 0.8*sum_c att_c*max(v_c,0)
        {
            const int h = (tid >> 6) & 3, half = tid >> 8, lane = tid & 63;
            const float k02 = g_K[l * Hv + h];   // pre-scaled by 0.2
            const f32x2_t zero2 = {0.f, 0.f};
            for (int it = 0; it < 8; ++it) {
                int e = (half * 8 + it) * 64 + lane;
                int s = edge_index[e], t = edge_index[Ev + e];
                float ea = edge_attr[e];
                f32x2_t ea2 = {ea, ea};
                f32x2_t acc2 = {0.f, 0.f};
                int bs = s * PAD + h * 32, bt = t * PAD + h * 32;
                #pragma unroll
                for (int c = 0; c < 32; c += 2) {
                    f32x2_t xl2 = unpack2v(*(const unsigned int*)&xls[bs + c]);
                    f32x2_t xr2 = unpack2v(*(const unsigned int*)&xrs[bt + c]);
                    f32x2_t we2 = *(const f32x2_t*)&wecol[h * 32 + c];
                    f32x2_t at2 = *(const f32x2_t*)&attv [h * 32 + c];
                    f32x2_t v   = xl2 + xr2 + ea2 * we2;
                    acc2 += at2 * __builtin_elementwise_max(v, zero2);
                }
                float dL = red [s * 8 + h * 2] + red [s * 8 + h * 2 + 1];
                float dR = red2[t * 8 + h * 2] + red2[t * 8 + h * 2 + 1];
                float alpha = 0.2f * (dL + dR) + k02 * ea + 0.8f * (acc2.x + acc2.y);
                alphas[e * Hv + h] = f2b(alpha);
            }
        }
        __syncthreads();

        // ---- per (dst, head, half): softmax-fused gather + LN + ELU + residual ----
        {
            const int t = tid & 63, h = (tid >> 6) & 3, half = tid >> 8;
            const int ch0 = h * 32 + half * 16;
            int beg = csr_off[t], end = csr_off[t + 1];
            float mx = -3e38f;
            for (int idx = beg; idx < end; ++idx)
                mx = fmaxf(mx, b2f(alphas[csr_eid[idx] * Hv + h]));
            f32x2_t acc2[8];
            #pragma unroll
            for (int j = 0; j < 8; ++j) acc2[j] = (f32x2_t){0.f, 0.f};
            float den = 0.f;
            for (int idx = beg; idx < end; ++idx) {
                int e = csr_eid[idx];
                int s = edge_index[e];
                float ex = expf(b2f(alphas[e * Hv + h]) - mx);
                den += ex;
                f32x2_t ex2 = {ex, ex};
                int bs = s * PAD + ch0;
                #pragma unroll
                for (int j = 0; j < 8; ++j)
                    acc2[j] += ex2 * unpack2v(*(const unsigned int*)&xls[bs + 2 * j]);
            }
            float inv_den = (end > beg) ? 1.f / den : 0.f;
            f32x2_t id2 = {inv_den, inv_den};
            f32x2_t sum2 = {0.f, 0.f}, sq2 = {0.f, 0.f};
            #pragma unroll
            for (int j = 0; j < 8; ++j) {
                f32x2_t cb = *(const f32x2_t*)&conv_bias[l * Dv + ch0 + 2 * j];
                f32x2_t g  = acc2[j] * id2 + cb;
                acc2[j] = g;
                sum2 += g; sq2 += g * g;
            }
            red [t * 8 + h * 2 + half] = sum2.x + sum2.y;
            red2[t * 8 + h * 2 + half] = sq2.x + sq2.y;
            __syncthreads();
            float mu = 0.f, ms = 0.f;
            #pragma unroll
            for (int j = 0; j < 8; ++j) { mu += red[t * 8 + j]; ms += red2[t * 8 + j]; }
            mu *= (1.f / 128.f); ms *= (1.f / 128.f);
            float rstd = rsqrtf(ms - mu * mu + 1e-5f);
            f32x2_t mu2 = {mu, mu}, rs2 = {rstd, rstd};
            #pragma unroll
            for (int j = 0; j < 8; ++j) {
                f32x2_t lg = *(const f32x2_t*)&ln_g[l * Dv + ch0 + 2 * j];
                f32x2_t lb = *(const f32x2_t*)&ln_b[l * Dv + ch0 + 2 * j];
                f32x2_t g  = (acc2[j] - mu2) * rs2 * lg + lb;
                g.x = g.x > 0.f ? g.x : (expf(g.x) - 1.f);
                g.y = g.y > 0.f ? g.y : (expf(g.y) - 1.f);
                unsigned int* hp = (unsigned int*)&hs[t * PAD + ch0 + 2 * j];
                f32x2_t hv = unpack2v(*hp) + g;      // residual
                *hp = pack2v(hv);
            }
        }
        __syncthreads();
    }

    // ---- hat_T (f32 out); T0 -> xrs; preload W2 ----
    if (tid < Dv) wecol[tid] = W2[tid];
    for (int idx = tid; idx < Nv * Dv; idx += 512) {
        int n = idx >> 7, d = idx & 127;
        float t0 = (attr_emb[n * Dv + d] + opt_emb[(n * Kv + x[b * Nv + n]) * Dv + d])
                   * prior[n];
        xrs[n * PAD + d] = f2b(t0);
        size_t rb = ((size_t)(b * Nv + n)) * (2 * Dv);
        out_hatT[rb + d]      = t0;
        out_hatT[rb + Dv + d] = b2f(hs[n * PAD + d]);
    }
    __syncthreads();

    // ---- hidden = relu([T0,h] @ W1 + b1) -> xls  (MFMA, K=256) ----
    // wave w (0..7): cols w*16..w*16+15.
    {
        const int w = tid >> 6, lane = tid & 63;
        const int row16 = lane & 15, kg = lane >> 4;
        f32x4_t acc[4];
        #pragma unroll
        for (int mt = 0; mt < 4; ++mt)
            acc[mt] = (f32x4_t){0.f, 0.f, 0.f, 0.f};

        #pragma unroll
        for (int kk = 0; kk < 8; ++kk) {
            const bf16* asrc = (kk < 4) ? xrs : hs;   // T0 then h
            const int kb = (kk & 3) * 32 + kg * 8;
            bf16x8_t a[4];
            #pragma unroll
            for (int mt = 0; mt < 4; ++mt)
                a[mt] = load_a_frag(asrc, (mt * 16 + row16) * PAD + kb);
            const int f = kk * 8 + w;
            bf16x8_t bh  = *(const bf16x8_t*)&g_pW1[(size_t)(f * 64 + lane) * 8];
            bf16x8_t blo = *(const bf16x8_t*)&g_pW1[(size_t)2 * Dv * Dv + (size_t)(f * 64 + lane) * 8];
            #pragma unroll
            for (int mt = 0; mt < 4; ++mt) {
                acc[mt] = __builtin_amdgcn_mfma_f32_16x16x32_bf16(a[mt], bh,  acc[mt], 0, 0, 0);
                acc[mt] = __builtin_amdgcn_mfma_f32_16x16x32_bf16(a[mt], blo, acc[mt], 0, 0, 0);
            }
        }
        #pragma unroll
        for (int mt = 0; mt < 4; ++mt) {
            const int col = w * 16 + row16;
            #pragma unroll
            for (int r = 0; r < 4; ++r) {
                const int row = mt * 16 + kg * 4 + r;
                float v = acc[mt][r] + b1[col];
                xls[row * PAD + col] = f2b(v > 0.f ? v : 0.f);
            }
        }
    }
    __syncthreads();

    // ---- rel = sigmoid(hidden @ W2 + b2) (f32 out) ----
    {
        const int t = tid & 63, h = (tid >> 6) & 3, half = tid >> 8;
        const int ch0 = h * 32 + half * 16;
        f32x2_t s2 = {0.f, 0.f};
        #pragma unroll
        for (int c = 0; c < 16; c += 2) {
            f32x2_t h2 = unpack2v(*(const unsigned int*)&xls[t * PAD + ch0 + c]);
            s2 += h2 * *(const f32x2_t*)&wecol[ch0 + c];
        }
        red[t * 8 + h * 2 + half] = s2.x + s2.y;
        __syncthreads();
        if (h == 0 && half == 0) {
            float z = b2[0];
            #pragma unroll
            for (int j = 0; j < 8; ++j) z += red[t * 8 + j];
            float r = 1.f / (1.f + expf(-z));
            relbuf[t] = r;
            out_rel[b * Nv + t] = r;
        }
    }
    __syncthreads();

    // ---- f_scale (f32 out) ----
    if (tid < Dv) {
        float num = 0.f, den = 0.f;
        for (int n = 0; n < Nv; ++n) {
            float r = relbuf[n];
            num += b2f(hs[n * PAD + tid]) * r;
            den += r;
        }
        out_fscale[b * Dv + tid] = num / (den + 1e-8f);
    }
}

extern "C" void kernel_launch(void* const* d_in, const int* in_sizes, int n_in,
                              void* d_out, int out_size, void* d_ws, size_t ws_size,
                              hipStream_t stream)
{
    const int*   x          = (const int*)  d_in[0];
    const int*   edge_index = (const int*)  d_in[1];
    const float* edge_attr  = (const float*)d_in[2];
    const float* attr_emb   = (const float*)d_in[3];
    const float* opt_emb    = (const float*)d_in[4];
    const float* prior      = (const float*)d_in[5];
    const float* Wl         = (const float*)d_in[6];
    const float* bl         = (const float*)d_in[7];
    const float* Wr         = (const float*)d_in[8];
    const float* br         = (const float*)d_in[9];
    const float* We         = (const float*)d_in[10];
    const float* att        = (const float*)d_in[11];
    const float* conv_bias  = (const float*)d_in[12];
    const float* ln_g       = (const float*)d_in[13];
    const float* ln_b       = (const float*)d_in[14];
    const float* W1         = (const float*)d_in[15];
    const float* b1         = (const float*)d_in[16];
    const float* W2         = (const float*)d_in[17];
    const float* b2         = (const float*)d_in[18];

    int* csr_off = (int*)d_ws;          // Nv+1 ints (128 reserved)
    int* csr_eid = (int*)d_ws + 128;    // Ev ints

    float* out        = (float*)d_out;
    float* out_fscale = out;                                      // B*D
    float* out_rel    = out + (size_t)Bv * Dv;                    // B*N
    float* out_hatT   = out + (size_t)Bv * Dv + (size_t)Bv * Nv;  // B*N*2D

    prep<<<65, 256, 0, stream>>>(edge_index, csr_off, csr_eid, Wl, Wr, W1, We, att);
    gat_fused<<<Bv, 512, 0, stream>>>(x, edge_index, edge_attr, attr_emb, opt_emb,
                                      prior, bl, br, conv_bias,
                                      ln_g, ln_b, b1, W2, b2, We, att,
                                      csr_off, csr_eid,
                                      out_fscale, out_rel, out_hatT);
}

// Round 6
// 281.163 us; speedup vs baseline: 2.9596x; 1.0767x over previous
//
#include <hip/hip_runtime.h>
#include <hip/hip_bf16.h>

#define Bv 1024
#define Nv 64
#define Ev 1024
#define Dv 128
#define Hv 4
#define Lv 2
#define Kv 5
#define PAD 130   // bf16 LDS row stride

typedef __hip_bfloat16 bf16;
typedef __attribute__((ext_vector_type(8))) short bf16x8_t;  // 8 bf16 in 4 VGPRs
typedef __attribute__((ext_vector_type(4))) float f32x4_t;   // MFMA accum
typedef __attribute__((ext_vector_type(2))) float f32x2_t;   // packed dual-f32 (v_pk_*)

__device__ __forceinline__ float b2f(bf16 v) { return __bfloat162float(v); }
__device__ __forceinline__ bf16  f2b(float v) { return __float2bfloat16(v); }

// Packed MFMA B-fragment weights (bf16 hi/lo planes) in device-global memory.
__device__ bf16 g_pWl[(size_t)Lv * 2 * Dv * Dv];   // [L][2 planes][128*128]
__device__ bf16 g_pWr[(size_t)Lv * 2 * Dv * Dv];   // [L][2 planes][128*128]
__device__ bf16 g_pW1[(size_t)2 * 2 * Dv * Dv];    // [2 planes][256*128]
__device__ float g_K[Lv * Hv];                     // 0.2 * sum_c att[l,h,c]*We[l,h,c]
// CSR-sorted edge tables (built once by prep, copied to LDS by every block):
__device__ unsigned short g_spk[Ev];               // src | dst<<6
__device__ float          g_sea[Ev];               // edge_attr in sorted order
__device__ int            g_off[Nv + 1];           // per-dst bucket offsets

__device__ __forceinline__ f32x2_t unpack2v(unsigned int u) {
    union { unsigned int u; float f; } a, b;
    a.u = u << 16;
    b.u = u & 0xffff0000u;
    return (f32x2_t){a.f, b.f};
}

// pack 2 floats -> u32 of 2 bf16 (lo = elem0, hi = elem1)
__device__ __forceinline__ unsigned int pack2v(f32x2_t v) {
    union { bf16 b; unsigned short u; } lo, hi;
    lo.b = f2b(v.x); hi.b = f2b(v.y);
    return (unsigned int)lo.u | ((unsigned int)hi.u << 16);
}

// load 8 consecutive bf16 (element index even) from LDS as 4 dwords -> frag
__device__ __forceinline__ bf16x8_t load_a_frag(const bf16* buf, int elem_idx) {
    const unsigned int* p = (const unsigned int*)buf;
    union { bf16x8_t v; unsigned int u[4]; } r;
    int d = elem_idx >> 1;
    r.u[0] = p[d]; r.u[1] = p[d + 1]; r.u[2] = p[d + 2]; r.u[3] = p[d + 3];
    return r.v;
}

// ---------------- weight packing into MFMA B-fragment order ----------------
//   frag f = kk*8 + nt  (kk = k-step of 32, nt = 16-col tile)
//   element e = (f*64 + lane)*8 + i ;  col = nt*16 + (lane&15) ;
//   k = kk*32 + (lane>>4)*8 + i
__device__ void pack_mat(const float* __restrict__ W, bf16* __restrict__ out,
                         int K, int tid, int nth)
{
    const int total = K * 128;  // elements per plane
    for (int e = tid; e < total; e += nth) {
        int f    = e >> 9;          // 64 lanes * 8 elems
        int rem  = e & 511;
        int lane = rem >> 3;
        int i    = rem & 7;
        int kk   = f >> 3;
        int nt   = f & 7;
        int col  = nt * 16 + (lane & 15);
        int k    = kk * 32 + (lane >> 4) * 8 + i;
        float w  = W[k * 128 + col];
        bf16 hi  = f2b(w);
        out[e]         = hi;
        out[total + e] = f2b(w - b2f(hi));
    }
}

// ---------------- prep: block 0 = CSR sort; blocks 1.. = weight packing ----------------
__global__ void prep(const int* __restrict__ edge_index, const float* __restrict__ edge_attr,
                     const float* __restrict__ Wl, const float* __restrict__ Wr,
                     const float* __restrict__ W1, const float* __restrict__ We,
                     const float* __restrict__ att)
{
    const int bid = blockIdx.x;
    if (bid == 0) {
        __shared__ int cnt[Nv];
        int tid = threadIdx.x;
        if (tid < Nv) cnt[tid] = 0;
        __syncthreads();
        for (int e = tid; e < Ev; e += blockDim.x)
            atomicAdd(&cnt[edge_index[Ev + e]], 1);
        __syncthreads();
        if (tid == 0) {
            int s = 0;
            for (int t = 0; t < Nv; ++t) { int c = cnt[t]; g_off[t] = s; cnt[t] = s; s += c; }
            g_off[Nv] = s;
        }
        __syncthreads();
        for (int e = tid; e < Ev; e += blockDim.x) {
            int s = edge_index[e];
            int d = edge_index[Ev + e];
            int pos = atomicAdd(&cnt[d], 1);
            g_spk[pos] = (unsigned short)(s | (d << 6));
            g_sea[pos] = edge_attr[e];
        }
        return;
    }
    const int nth = (gridDim.x - 1) * 256;
    const int tid = (bid - 1) * 256 + threadIdx.x;
    for (int l = 0; l < Lv; ++l) {
        pack_mat(Wl + (size_t)l * Dv * Dv, g_pWl + (size_t)l * 2 * Dv * Dv, Dv, tid, nth);
        pack_mat(Wr + (size_t)l * Dv * Dv, g_pWr + (size_t)l * 2 * Dv * Dv, Dv, tid, nth);
    }
    pack_mat(W1, g_pW1, 2 * Dv, tid, nth);
    if (bid == 1 && threadIdx.x < Lv * Hv) {
        int l = threadIdx.x / Hv, h = threadIdx.x % Hv;
        float k = 0.f;
        for (int c = 0; c < 32; ++c)
            k += att[l * Dv + h * 32 + c] * We[l * Dv + h * 32 + c];
        g_K[threadIdx.x] = 0.2f * k;
    }
}

// ---------------- fused per-batch-element kernel (512 thr / 8 waves) ----------------
// launch_bounds (512, 2): VGPR budget 256. (512,4) forced 64 VGPRs -> ~776 MB/dispatch
// of scratch spill traffic -> HBM-bound. Do not tighten.
__global__ __launch_bounds__(512, 2)
void gat_fused(const int* __restrict__ x,
               const float* __restrict__ attr_emb,
               const float* __restrict__ opt_emb, const float* __restrict__ prior,
               const float* __restrict__ bl, const float* __restrict__ br,
               const float* __restrict__ conv_bias, const float* __restrict__ ln_g,
               const float* __restrict__ ln_b,
               const float* __restrict__ b1, const float* __restrict__ W2,
               const float* __restrict__ b2,
               const float* __restrict__ We, const float* __restrict__ att,
               float* __restrict__ out_fscale, float* __restrict__ out_rel,
               float* __restrict__ out_hatT)
{
    const int b = blockIdx.x;
    const int tid = threadIdx.x;

    __shared__ __align__(16) bf16 hs [Nv * PAD];
    __shared__ __align__(16) bf16 xls[Nv * PAD];
    __shared__ __align__(16) bf16 xrs[Nv * PAD];
    __shared__ bf16 alphas[Ev * Hv];               // sorted-position-major
    __shared__ __align__(16) float red [Nv * 8];   // also: dotL during logits
    __shared__ __align__(16) float red2[Nv * 8];   // also: dotR during logits
    __shared__ __align__(16) float wecol[Dv];
    __shared__ __align__(16) float attv [Dv];
    __shared__ float relbuf[Nv];
    // edge tables, all-LDS hot loops (no global indirection in layer body):
    __shared__ __align__(16) unsigned short spk[Ev];   // src | dst<<6
    __shared__ __align__(16) float sea[Ev];
    __shared__ int off[Nv + 1];

    // ---- table preload + T0 -> hs ----
    for (int i = tid; i < Ev; i += 512) {
        spk[i] = g_spk[i];
        sea[i] = g_sea[i];
    }
    if (tid < Nv + 1) off[tid] = g_off[tid];
    for (int idx = tid; idx < Nv * Dv; idx += 512) {
        int n = idx >> 7, d = idx & 127;
        float t0 = (attr_emb[n * Dv + d] + opt_emb[(n * Kv + x[b * Nv + n]) * Dv + d])
                   * prior[n];
        hs[n * PAD + d] = f2b(t0);
    }

    for (int l = 0; l < Lv; ++l) {
        if (tid < Dv) {
            wecol[tid] = We[l * Dv + tid];
            attv[tid]  = att[l * Dv + tid];
        }
        __syncthreads();

        // ---- GEMM via MFMA: [xl | xr] = h @ [Wl | Wr] + [bl | br] ----
        // wave w (0..7): waves 0-3 -> Wl cols (w&3)*32.. ; waves 4-7 -> Wr.
        {
            const int w = tid >> 6, lane = tid & 63;
            const int row16 = lane & 15, kg = lane >> 4;
            const bf16* pB = (w < 4) ? (g_pWl + (size_t)l * 2 * Dv * Dv)
                                     : (g_pWr + (size_t)l * 2 * Dv * Dv);
            const int wc = (w & 3) * 32;
            f32x4_t acc[4][2];
            #pragma unroll
            for (int mt = 0; mt < 4; ++mt)
                #pragma unroll
                for (int nt = 0; nt < 2; ++nt)
                    acc[mt][nt] = (f32x4_t){0.f, 0.f, 0.f, 0.f};

            #pragma unroll
            for (int kk = 0; kk < 4; ++kk) {
                const int kb = kk * 32 + kg * 8;
                bf16x8_t a[4];
                #pragma unroll
                for (int mt = 0; mt < 4; ++mt)
                    a[mt] = load_a_frag(hs, (mt * 16 + row16) * PAD + kb);
                #pragma unroll
                for (int nt = 0; nt < 2; ++nt) {
                    const int f = kk * 8 + (w & 3) * 2 + nt;
                    bf16x8_t bh  = *(const bf16x8_t*)&pB[(size_t)(f * 64 + lane) * 8];
                    bf16x8_t blo = *(const bf16x8_t*)&pB[Dv * Dv + (size_t)(f * 64 + lane) * 8];
                    #pragma unroll
                    for (int mt = 0; mt < 4; ++mt) {
                        acc[mt][nt] = __builtin_amdgcn_mfma_f32_16x16x32_bf16(
                                          a[mt], bh, acc[mt][nt], 0, 0, 0);
                        acc[mt][nt] = __builtin_amdgcn_mfma_f32_16x16x32_bf16(
                                          a[mt], blo, acc[mt][nt], 0, 0, 0);
                    }
                }
            }
            bf16* dst = (w < 4) ? xls : xrs;
            const float* bias = (w < 4) ? (bl + l * Dv) : (br + l * Dv);
            #pragma unroll
            for (int mt = 0; mt < 4; ++mt)
                #pragma unroll
                for (int nt = 0; nt < 2; ++nt) {
                    const int col = wc + nt * 16 + row16;
                    #pragma unroll
                    for (int r = 0; r < 4; ++r) {
                        const int row = mt * 16 + kg * 4 + r;
                        dst[row * PAD + col] = f2b(acc[mt][nt][r] + bias[col]);
                    }
                }
        }
        __syncthreads();

        // ---- per (n,h,half): linear att-dots (factored leaky-relu) -> red/red2 ----
        {
            const int t = tid & 63, h = (tid >> 6) & 3, half = tid >> 8;
            const int ch0 = h * 32 + half * 16;
            f32x2_t dl2 = {0.f, 0.f}, dr2 = {0.f, 0.f};
            #pragma unroll
            for (int c = 0; c < 16; c += 2) {
                f32x2_t a2 = *(const f32x2_t*)&attv[ch0 + c];
                dl2 += a2 * unpack2v(*(const unsigned int*)&xls[t * PAD + ch0 + c]);
                dr2 += a2 * unpack2v(*(const unsigned int*)&xrs[t * PAD + ch0 + c]);
            }
            red [t * 8 + h * 2 + half] = dl2.x + dl2.y;
            red2[t * 8 + h * 2 + half] = dr2.x + dr2.y;
        }
        __syncthreads();

        // ---- per-edge per-head logits over SORTED positions (all-LDS) ----
        // alpha = 0.2*(dotL[s]+dotR[t]+ea*K) + 0.8*sum_c att_c*max(v_c,0)
        {
            const int h = (tid >> 6) & 3, half = tid >> 8, lane = tid & 63;
            const float k02 = g_K[l * Hv + h];   // pre-scaled by 0.2
            const f32x2_t zero2 = {0.f, 0.f};
            for (int it = 0; it < 8; ++it) {
                int pos = (half * 8 + it) * 64 + lane;
                int pk = spk[pos];
                int s = pk & 63, t = (pk >> 6) & 63;
                float ea = sea[pos];
                f32x2_t ea2 = {ea, ea};
                f32x2_t acc2 = {0.f, 0.f};
                int bs = s * PAD + h * 32, bt = t * PAD + h * 32;
                #pragma unroll
                for (int c = 0; c < 32; c += 2) {
                    f32x2_t xl2 = unpack2v(*(const unsigned int*)&xls[bs + c]);
                    f32x2_t xr2 = unpack2v(*(const unsigned int*)&xrs[bt + c]);
                    f32x2_t we2 = *(const f32x2_t*)&wecol[h * 32 + c];
                    f32x2_t at2 = *(const f32x2_t*)&attv [h * 32 + c];
                    f32x2_t v   = xl2 + xr2 + ea2 * we2;
                    acc2 += at2 * __builtin_elementwise_max(v, zero2);
                }
                float dL = red [s * 8 + h * 2] + red [s * 8 + h * 2 + 1];
                float dR = red2[t * 8 + h * 2] + red2[t * 8 + h * 2 + 1];
                float alpha = 0.2f * (dL + dR) + k02 * ea + 0.8f * (acc2.x + acc2.y);
                alphas[pos * Hv + h] = f2b(alpha);
            }
        }
        __syncthreads();

        // ---- per (dst, head, half): softmax-fused gather + LN + ELU + residual ----
        // max pass: contiguous LDS scan, no indices. gather: 1-level LDS chain.
        {
            const int t = tid & 63, h = (tid >> 6) & 3, half = tid >> 8;
            const int ch0 = h * 32 + half * 16;
            int beg = off[t], end = off[t + 1];
            float mx = -3e38f;
            for (int idx = beg; idx < end; ++idx)
                mx = fmaxf(mx, b2f(alphas[idx * Hv + h]));
            f32x2_t acc2[8];
            #pragma unroll
            for (int j = 0; j < 8; ++j) acc2[j] = (f32x2_t){0.f, 0.f};
            float den = 0.f;
            for (int idx = beg; idx < end; ++idx) {
                int s = spk[idx] & 63;
                float ex = expf(b2f(alphas[idx * Hv + h]) - mx);
                den += ex;
                f32x2_t ex2 = {ex, ex};
                int bs = s * PAD + ch0;
                #pragma unroll
                for (int j = 0; j < 8; ++j)
                    acc2[j] += ex2 * unpack2v(*(const unsigned int*)&xls[bs + 2 * j]);
            }
            float inv_den = (end > beg) ? 1.f / den : 0.f;
            f32x2_t id2 = {inv_den, inv_den};
            f32x2_t sum2 = {0.f, 0.f}, sq2 = {0.f, 0.f};
            #pragma unroll
            for (int j = 0; j < 8; ++j) {
                f32x2_t cb = *(const f32x2_t*)&conv_bias[l * Dv + ch0 + 2 * j];
                f32x2_t g  = acc2[j] * id2 + cb;
                acc2[j] = g;
                sum2 += g; sq2 += g * g;
            }
            red [t * 8 + h * 2 + half] = sum2.x + sum2.y;
            red2[t * 8 + h * 2 + half] = sq2.x + sq2.y;
            __syncthreads();
            float mu = 0.f, ms = 0.f;
            #pragma unroll
            for (int j = 0; j < 8; ++j) { mu += red[t * 8 + j]; ms += red2[t * 8 + j]; }
            mu *= (1.f / 128.f); ms *= (1.f / 128.f);
            float rstd = rsqrtf(ms - mu * mu + 1e-5f);
            f32x2_t mu2 = {mu, mu}, rs2 = {rstd, rstd};
            #pragma unroll
            for (int j = 0; j < 8; ++j) {
                f32x2_t lg = *(const f32x2_t*)&ln_g[l * Dv + ch0 + 2 * j];
                f32x2_t lb = *(const f32x2_t*)&ln_b[l * Dv + ch0 + 2 * j];
                f32x2_t g  = (acc2[j] - mu2) * rs2 * lg + lb;
                g.x = g.x > 0.f ? g.x : (expf(g.x) - 1.f);
                g.y = g.y > 0.f ? g.y : (expf(g.y) - 1.f);
                unsigned int* hp = (unsigned int*)&hs[t * PAD + ch0 + 2 * j];
                f32x2_t hv = unpack2v(*hp) + g;      // residual
                *hp = pack2v(hv);
            }
        }
        __syncthreads();
    }

    // ---- hat_T (f32 out); T0 -> xrs; preload W2 ----
    if (tid < Dv) wecol[tid] = W2[tid];
    for (int idx = tid; idx < Nv * Dv; idx += 512) {
        int n = idx >> 7, d = idx & 127;
        float t0 = (attr_emb[n * Dv + d] + opt_emb[(n * Kv + x[b * Nv + n]) * Dv + d])
                   * prior[n];
        xrs[n * PAD + d] = f2b(t0);
        size_t rb = ((size_t)(b * Nv + n)) * (2 * Dv);
        out_hatT[rb + d]      = t0;
        out_hatT[rb + Dv + d] = b2f(hs[n * PAD + d]);
    }
    __syncthreads();

    // ---- hidden = relu([T0,h] @ W1 + b1) -> xls  (MFMA, K=256) ----
    // wave w (0..7): cols w*16..w*16+15.
    {
        const int w = tid >> 6, lane = tid & 63;
        const int row16 = lane & 15, kg = lane >> 4;
        f32x4_t acc[4];
        #pragma unroll
        for (int mt = 0; mt < 4; ++mt)
            acc[mt] = (f32x4_t){0.f, 0.f, 0.f, 0.f};

        #pragma unroll
        for (int kk = 0; kk < 8; ++kk) {
            const bf16* asrc = (kk < 4) ? xrs : hs;   // T0 then h
            const int kb = (kk & 3) * 32 + kg * 8;
            bf16x8_t a[4];
            #pragma unroll
            for (int mt = 0; mt < 4; ++mt)
                a[mt] = load_a_frag(asrc, (mt * 16 + row16) * PAD + kb);
            const int f = kk * 8 + w;
            bf16x8_t bh  = *(const bf16x8_t*)&g_pW1[(size_t)(f * 64 + lane) * 8];
            bf16x8_t blo = *(const bf16x8_t*)&g_pW1[(size_t)2 * Dv * Dv + (size_t)(f * 64 + lane) * 8];
            #pragma unroll
            for (int mt = 0; mt < 4; ++mt) {
                acc[mt] = __builtin_amdgcn_mfma_f32_16x16x32_bf16(a[mt], bh,  acc[mt], 0, 0, 0);
                acc[mt] = __builtin_amdgcn_mfma_f32_16x16x32_bf16(a[mt], blo, acc[mt], 0, 0, 0);
            }
        }
        #pragma unroll
        for (int mt = 0; mt < 4; ++mt) {
            const int col = w * 16 + row16;
            #pragma unroll
            for (int r = 0; r < 4; ++r) {
                const int row = mt * 16 + kg * 4 + r;
                float v = acc[mt][r] + b1[col];
                xls[row * PAD + col] = f2b(v > 0.f ? v : 0.f);
            }
        }
    }
    __syncthreads();

    // ---- rel = sigmoid(hidden @ W2 + b2) (f32 out) ----
    {
        const int t = tid & 63, h = (tid >> 6) & 3, half = tid >> 8;
        const int ch0 = h * 32 + half * 16;
        f32x2_t s2 = {0.f, 0.f};
        #pragma unroll
        for (int c = 0; c < 16; c += 2) {
            f32x2_t h2 = unpack2v(*(const unsigned int*)&xls[t * PAD + ch0 + c]);
            s2 += h2 * *(const f32x2_t*)&wecol[ch0 + c];
        }
        red[t * 8 + h * 2 + half] = s2.x + s2.y;
        __syncthreads();
        if (h == 0 && half == 0) {
            float z = b2[0];
            #pragma unroll
            for (int j = 0; j < 8; ++j) z += red[t * 8 + j];
            float r = 1.f / (1.f + expf(-z));
            relbuf[t] = r;
            out_rel[b * Nv + t] = r;
        }
    }
    __syncthreads();

    // ---- f_scale (f32 out) ----
    if (tid < Dv) {
        float num = 0.f, den = 0.f;
        for (int n = 0; n < Nv; ++n) {
            float r = relbuf[n];
            num += b2f(hs[n * PAD + tid]) * r;
            den += r;
        }
        out_fscale[b * Dv + tid] = num / (den + 1e-8f);
    }
}

extern "C" void kernel_launch(void* const* d_in, const int* in_sizes, int n_in,
                              void* d_out, int out_size, void* d_ws, size_t ws_size,
                              hipStream_t stream)
{
    const int*   x          = (const int*)  d_in[0];
    const int*   edge_index = (const int*)  d_in[1];
    const float* edge_attr  = (const float*)d_in[2];
    const float* attr_emb   = (const float*)d_in[3];
    const float* opt_emb    = (const float*)d_in[4];
    const float* prior      = (const float*)d_in[5];
    const float* Wl         = (const float*)d_in[6];
    const float* bl         = (const float*)d_in[7];
    const float* Wr         = (const float*)d_in[8];
    const float* br         = (const float*)d_in[9];
    const float* We         = (const float*)d_in[10];
    const float* att        = (const float*)d_in[11];
    const float* conv_bias  = (const float*)d_in[12];
    const float* ln_g       = (const float*)d_in[13];
    const float* ln_b       = (const float*)d_in[14];
    const float* W1         = (const float*)d_in[15];
    const float* b1         = (const float*)d_in[16];
    const float* W2         = (const float*)d_in[17];
    const float* b2         = (const float*)d_in[18];

    float* out        = (float*)d_out;
    float* out_fscale = out;                                      // B*D
    float* out_rel    = out + (size_t)Bv * Dv;                    // B*N
    float* out_hatT   = out + (size_t)Bv * Dv + (size_t)Bv * Nv;  // B*N*2D

    prep<<<129, 256, 0, stream>>>(edge_index, edge_attr, Wl, Wr, W1, We, att);
    gat_fused<<<Bv, 512, 0, stream>>>(x, attr_emb, opt_emb,
                                      prior, bl, br, conv_bias,
                                      ln_g, ln_b, b1, W2, b2, We, att,
                                      out_fscale, out_rel, out_hatT);
}